// Round 5
// baseline (269.262 us; speedup 1.0000x reference)
//
#include <hip/hip_runtime.h>
#include <math.h>

// R20: R18/R19 grid-barrier fused kernels both crashed the container (barrier
// deadlock or infra — indistinguishable). Abandon in-kernel grid sync. The
// dispatch-overhead lever survives WITHOUT it: restructure so dependent work
// shares a block. (a) attnout_kernel: one block = 16 tokens x ALL 8 heads x
// both streams (16 wave-units, 4 waves x 4 serial) -> O kept in LDS ->
// outcomp GEMM+GELU+store in the same block. AO never touches HBM; no
// cross-block dependency. (b) qkvprep_kernel: R15's proven in-block X
// staging (stage_x_row) + 3 GEMMs + wprep folded in as 8 extra blocks.
// TOTAL: 2 dispatches, no barriers/atomics/memset. All inner math
// byte-identical to verified kernels (R15 qkv, R19 attn body, R17 outcomp).
#define BATCH 2
#define C 64
#define HH 48
#define WW 48
#define NTOK 2304
#define HEADS 8
#define KVSTRIDE 12

typedef unsigned short bf16_t;
typedef __attribute__((ext_vector_type(8))) short bf16x8;
typedef __attribute__((ext_vector_type(4))) float f32x4;

__device__ __forceinline__ bf16_t f2bf(float f) {
    unsigned int u = __float_as_uint(f);
    u = (u + 0x7fffu + ((u >> 16) & 1u)) >> 16;   // RNE
    return (bf16_t)u;
}
__device__ __forceinline__ unsigned pack2(float a, float b) {
    return (unsigned)f2bf(a) | ((unsigned)f2bf(b) << 16);
}
__device__ __forceinline__ float4 ld_bf4(const bf16_t* p) {
    uint2 v = *(const uint2*)p;
    float4 r;
    r.x = __uint_as_float(v.x << 16); r.y = __uint_as_float(v.x & 0xffff0000u);
    r.z = __uint_as_float(v.y << 16); r.w = __uint_as_float(v.y & 0xffff0000u);
    return r;
}

// Stage one token-row of X. strm 0: rgb transpose gather. strm 1: conv1x1+
// ReLU+bilinear x2 (half-pixel; clamp == jax edge renorm for 24->48).
__device__ __forceinline__ void stage_x_row(
    float* xrow, const float* rgb, const float* dep,
    const float* w_exp, const float* b_exp,
    int b, int n, int strm, int c0, int cstep)
{
    int wi = n / HH, hi = n % HH;
    if (strm == 0) {
        const float* base = rgb + (size_t)b * C * NTOK + (size_t)hi * WW + wi;
        for (int c = c0; c < 64; c += cstep)
            xrow[c] = base[(size_t)c * NTOK];
    } else {
        float cy = 0.5f * hi - 0.25f, cx = 0.5f * wi - 0.25f;
        float fy0 = floorf(cy), fx0 = floorf(cx);
        float fy = cy - fy0, fx = cx - fx0;
        int y0 = max((int)fy0, 0), x0 = max((int)fx0, 0);
        int y1 = min((int)fy0 + 1, 23), x1 = min((int)fx0 + 1, 23);
        const float* dp = dep + b * 576;
        float d00 = dp[y0*24 + x0], d01 = dp[y0*24 + x1];
        float d10 = dp[y1*24 + x0], d11 = dp[y1*24 + x1];
        for (int c = c0; c < 64; c += cstep) {
            float w = w_exp[c], bb = b_exp[c];
            float r00 = fmaxf(w*d00 + bb, 0.f), r01 = fmaxf(w*d01 + bb, 0.f);
            float r10 = fmaxf(w*d10 + bb, 0.f), r11 = fmaxf(w*d11 + bb, 0.f);
            xrow[c] = (1.f-fy)*((1.f-fx)*r00 + fx*r01) + fy*((1.f-fx)*r10 + fx*r11);
        }
    }
}

// ===========================================================================
// MAIN PATH: 2 dispatches.
// ===========================================================================

// Kernel A: grid(152). Blocks 0..143: fused prep + Q,K,V GEMMs per
// (tile 0..35, z=b*2+strm); X staged in-block (R15 proven). Blocks 144..151:
// wprep (W1 = Wc[:,:64]@Wrp ; W2 = Wc[:,64:]@Wdp ; beff = Wc@[br;bd]+bc).
// Q,K -> [sb][h][n][8] bf16 (Q pre-scaled by 1/8*log2e); V -> [sb][h][d][n].
__global__ __launch_bounds__(256) void qkvprep_kernel(
    const float* __restrict__ rgb, const float* __restrict__ dep,
    const float* __restrict__ w_exp, const float* __restrict__ b_exp,
    const float* __restrict__ w_rq, const float* __restrict__ w_rk,
    const float* __restrict__ w_rv,
    const float* __restrict__ w_dq, const float* __restrict__ w_dk,
    const float* __restrict__ w_dv,
    const float* __restrict__ w_rp, const float* __restrict__ w_dp,
    const float* __restrict__ w_comp,
    const float* __restrict__ b_rp, const float* __restrict__ b_dp,
    const float* __restrict__ b_comp,
    bf16_t* __restrict__ Qb, bf16_t* __restrict__ Kb, bf16_t* __restrict__ VT,
    float* __restrict__ W1, float* __restrict__ W2, float* __restrict__ beff)
{
    __shared__ float Xs[64][68];
    __shared__ float Ws[64][68];
    int bid = blockIdx.x;
    int tid = threadIdx.x;

    if (bid < 144) {
        int tile = bid % 36, z = bid / 36;
        int b = z >> 1, strm = z & 1;
        int sb = strm*2 + b;
        {
            int r = tid & 63, c0 = tid >> 6;
            stage_x_row(&Xs[r][0], rgb, dep, w_exp, b_exp, b, tile*64 + r, strm, c0, 4);
        }
        int sr = tid >> 4, sc = (tid & 15) * 4;
        int ty = tid >> 4, tx = tid & 15;

        #pragma unroll
        for (int m = 0; m < 3; ++m) {
            const float* W = strm ? (m == 0 ? w_dq : m == 1 ? w_dk : w_dv)
                                  : (m == 0 ? w_rq : m == 1 ? w_rk : w_rv);
            __syncthreads();   // Xs ready (m=0) / prior GEMM done reading Ws
            #pragma unroll
            for (int rr = 0; rr < 4; ++rr) {
                int r = rr*16 + sr;
                *(float4*)&Ws[r][sc] = *(const float4*)&W[r*64 + sc];
            }
            __syncthreads();

            float acc[4][4] = {};
            #pragma unroll
            for (int k = 0; k < 64; k += 4) {
                float4 xv[4], wv4[4];
                #pragma unroll
                for (int i = 0; i < 4; ++i) xv[i] = *(const float4*)&Xs[4*ty + i][k];
                #pragma unroll
                for (int j = 0; j < 4; ++j) wv4[j] = *(const float4*)&Ws[tx + 16*j][k];
                #pragma unroll
                for (int i = 0; i < 4; ++i)
                    #pragma unroll
                    for (int j = 0; j < 4; ++j)
                        acc[i][j] += xv[i].x*wv4[j].x + xv[i].y*wv4[j].y
                                   + xv[i].z*wv4[j].z + xv[i].w*wv4[j].w;
            }
            float scale = (m == 0) ? (0.35355339059327373f * 1.4426950408889634f) : 1.0f;
            #pragma unroll
            for (int j = 0; j < 4; ++j) {
                int o = tx + 16*j;
                int h = o >> 3, d = o & 7;
                #pragma unroll
                for (int i = 0; i < 4; ++i) {
                    int n = tile*64 + 4*ty + i;
                    bf16_t v = f2bf(acc[i][j] * scale);
                    if (m == 0)      Qb[(((size_t)sb*8 + h)*NTOK + n)*8 + d] = v;
                    else if (m == 1) Kb[(((size_t)sb*8 + h)*NTOK + n)*8 + d] = v;
                    else             VT[(((size_t)sb*8 + h)*8 + d)*NTOK + n] = v;
                }
            }
        }
    } else {
        int idx0 = bid - 144;
        int bx = idx0 & 3, m = idx0 >> 2;
        const float* Wp = m ? w_dp : w_rp;
        float* Wo = m ? W2 : W1;
        int sr = tid >> 4, sc4 = (tid & 15) * 4;
        #pragma unroll
        for (int rr = 0; rr < 4; ++rr) {
            int r = rr*16 + sr;
            *(float4*)&Xs[r][sc4] = *(const float4*)&Wp[r*64 + sc4];
        }
        __syncthreads();
        int r = tid >> 4;
        int o = bx*16 + r;
        int c4 = (tid & 15) * 4;
        float a0 = 0, a1 = 0, a2 = 0, a3 = 0;
        for (int j = 0; j < 64; ++j) {
            float wc = w_comp[o*128 + m*64 + j];
            float4 wp = *(const float4*)&Xs[j][c4];
            a0 += wc*wp.x; a1 += wc*wp.y; a2 += wc*wp.z; a3 += wc*wp.w;
        }
        Wo[o*64 + c4]     = a0;
        Wo[o*64 + c4 + 1] = a1;
        Wo[o*64 + c4 + 2] = a2;
        Wo[o*64 + c4 + 3] = a3;
        if (bx == 0 && m == 0 && tid < 64) {
            float s = b_comp[tid];
            for (int j = 0; j < 64; ++j)
                s += w_comp[tid*128 + j] * b_rp[j] + w_comp[tid*128 + 64 + j] * b_dp[j];
            beff[tid] = s;
        }
    }
}

// Kernel B: grid(288) = (tile 0..143, b 0..1). One block owns 16 tokens:
//  - attn: 16 units (which x head), 4 waves x 4 serial; MFMA flash, no-max
//    exp2 O_aug (proven R19 body); normalized O -> LDS AOls (never HBM).
//  - outcomp: 2x K=64 GEMM (W1,W2) + beff + GELU + LDS restage + coalesced
//    store (out[(b*C+o)*2304 + n], full 64B lines).
__global__ __launch_bounds__(256) void attnout_kernel(
    const bf16_t* __restrict__ Qb, const bf16_t* __restrict__ Kb,
    const bf16_t* __restrict__ VT,
    const float* __restrict__ W1, const float* __restrict__ W2,
    const float* __restrict__ beff, float* __restrict__ out)
{
    __shared__ __align__(16) bf16_t Pls[4][2][16][40];  // 10,240 B
    __shared__ __align__(16) float  Ols[4][16][16];     //  4,096 B
    __shared__ __align__(16) float  AOls[2][16][68];    //  8,704 B
    __shared__ __align__(16) float  Wsh[2][64][68];     // 34,816 B  (57,856 total)

    int bid = blockIdx.x;
    int tid = threadIdx.x;
    int tile = bid % 144, b = bid / 144;
    int n0 = tile * 16;

    // Stage W1/W2 up front (independent of attn; overlaps with Q/K loads).
    {
        int sr = tid >> 4, sc4 = (tid & 15) * 4;
        #pragma unroll
        for (int rr = 0; rr < 4; ++rr) {
            int r = rr*16 + sr;
            *(float4*)&Wsh[0][r][sc4] = *(const float4*)&W1[r*64 + sc4];
            *(float4*)&Wsh[1][r][sc4] = *(const float4*)&W2[r*64 + sc4];
        }
    }

    int t = tid & 63, w = tid >> 6;
    int m16 = t & 15, quad = t >> 4;
    const bf16x8 zf = {0,0,0,0,0,0,0,0};
    const bf16x8 onesf = {0x3F80,0x3F80,0x3F80,0x3F80,
                          0x3F80,0x3F80,0x3F80,0x3F80};
    const f32x4 cz = {0.f, 0.f, 0.f, 0.f};
    bf16_t* PA = &Pls[w][0][0][0];
    bf16_t* PB = &Pls[w][1][0][0];

    // 16 attn units: unit = w*4 + i -> which = unit>>3, h = unit&7.
    #pragma unroll 1
    for (int i = 0; i < 4; ++i) {
        int unit = w * 4 + i;
        int which = unit >> 3, h = unit & 7;
        int qsb = which * 2 + b;
        int ksb = (1 - which) * 2 + b;
        const bf16_t* Q  = Qb + ((size_t)qsb * 8 + h) * NTOK * 8;
        const bf16_t* K  = Kb + ((size_t)ksb * 8 + h) * NTOK * 8;
        const bf16_t* Vt = VT + ((size_t)ksb * 8 + h) * 8 * NTOK;  // [d][key]

        bf16x8 qf = (quad == 0) ? *(const bf16x8*)&Q[(size_t)(n0 + m16) * 8] : zf;
        f32x4 oacc = cz;

        #pragma unroll 1
        for (int cc = 0; cc < 36; ++cc) {
            int k0 = cc * 64;
            bf16x8 kA0 = (quad == 0) ? *(const bf16x8*)&K[(size_t)(k0 + m16) * 8]      : zf;
            bf16x8 kA1 = (quad == 0) ? *(const bf16x8*)&K[(size_t)(k0 + 16 + m16) * 8] : zf;
            bf16x8 kB0 = (quad == 0) ? *(const bf16x8*)&K[(size_t)(k0 + 32 + m16) * 8] : zf;
            bf16x8 kB1 = (quad == 0) ? *(const bf16x8*)&K[(size_t)(k0 + 48 + m16) * 8] : zf;
            bf16x8 vA = (m16 < 8) ? *(const bf16x8*)&Vt[(size_t)m16 * NTOK + k0 + quad * 8]
                      : (m16 == 8 ? onesf : zf);
            bf16x8 vB = (m16 < 8) ? *(const bf16x8*)&Vt[(size_t)m16 * NTOK + k0 + 32 + quad * 8]
                      : (m16 == 8 ? onesf : zf);

            f32x4 sA0 = __builtin_amdgcn_mfma_f32_16x16x32_bf16(qf, kA0, cz, 0, 0, 0);
            f32x4 sA1 = __builtin_amdgcn_mfma_f32_16x16x32_bf16(qf, kA1, cz, 0, 0, 0);
            f32x4 sB0 = __builtin_amdgcn_mfma_f32_16x16x32_bf16(qf, kB0, cz, 0, 0, 0);
            f32x4 sB1 = __builtin_amdgcn_mfma_f32_16x16x32_bf16(qf, kB1, cz, 0, 0, 0);

            #pragma unroll
            for (int q4 = 0; q4 < 4; ++q4) {
                float a0 = __builtin_amdgcn_exp2f(sA0[q4]);
                float a1 = __builtin_amdgcn_exp2f(sA1[q4]);
                float b0 = __builtin_amdgcn_exp2f(sB0[q4]);
                float b1 = __builtin_amdgcn_exp2f(sB1[q4]);
                PA[(quad*4 + q4)*40 + m16]      = (bf16_t)(__float_as_uint(a0) >> 16);
                PA[(quad*4 + q4)*40 + m16 + 16] = (bf16_t)(__float_as_uint(a1) >> 16);
                PB[(quad*4 + q4)*40 + m16]      = (bf16_t)(__float_as_uint(b0) >> 16);
                PB[(quad*4 + q4)*40 + m16 + 16] = (bf16_t)(__float_as_uint(b1) >> 16);
            }
            bf16x8 pfA = *(const bf16x8*)&PA[m16*40 + quad * 8];
            oacc = __builtin_amdgcn_mfma_f32_16x16x32_bf16(pfA, vA, oacc, 0, 0, 0);
            bf16x8 pfB = *(const bf16x8*)&PB[m16*40 + quad * 8];
            oacc = __builtin_amdgcn_mfma_f32_16x16x32_bf16(pfB, vB, oacc, 0, 0, 0);
        }

        #pragma unroll
        for (int q4 = 0; q4 < 4; ++q4)
            Ols[w][quad*4 + q4][m16] = oacc[q4];
        #pragma unroll
        for (int e = 0; e < 2; ++e) {
            int idx = t * 2 + e;           // 16 q x 8 d
            int qq = idx >> 3, d = idx & 7;
            AOls[which][qq][8*h + d] = Ols[w][qq][d] / Ols[w][qq][8];
        }
    }
    __syncthreads();   // all 16 units written; Wsh staged

    // ---- outcomp on the block's 16 tokens ----
    int tx = tid & 15, ty = tid >> 4;      // ty = token row 0..15
    float g[4] = {};
    #pragma unroll
    for (int k = 0; k < 64; k += 4) {
        float4 xr = *(const float4*)&AOls[0][ty][k];
        float4 xd = *(const float4*)&AOls[1][ty][k];
        #pragma unroll
        for (int jj = 0; jj < 4; ++jj) {
            float4 w1 = *(const float4*)&Wsh[0][tx + 16*jj][k];
            float4 w2 = *(const float4*)&Wsh[1][tx + 16*jj][k];
            g[jj] += xr.x*w1.x + xr.y*w1.y + xr.z*w1.z + xr.w*w1.w
                   + xd.x*w2.x + xd.y*w2.y + xd.z*w2.z + xd.w*w2.w;
        }
    }

    __syncthreads();                       // done reading Pls region? (Gs aliases Pls)
    float* Gs = (float*)&Pls[0][0][0][0];  // [64 o][stride 20] = 5,120 B
    #pragma unroll
    for (int jj = 0; jj < 4; ++jj) {
        int o = tx + 16*jj;
        float x = g[jj] + beff[o];
        float gl = 0.5f * x * (1.0f + erff(x * 0.70710678118654752f));
        Gs[o*20 + ty] = gl;
    }
    __syncthreads();
    {
        int o = tid >> 2, s = tid & 3;     // 64 o x 4 float4-segments
        float4 v = *(const float4*)&Gs[o*20 + 4*s];
        *(float4*)&out[((size_t)(b*C + o))*NTOK + n0 + 4*s] = v;
    }
}

// ===========================================================================
// FALLBACK (R9 big path, proven): ws >= 3,538,944 B.
// ===========================================================================
__global__ __launch_bounds__(256) void kv_all_kernel(
    const float* __restrict__ rgb, const float* __restrict__ dep,
    const float* __restrict__ w_exp, const float* __restrict__ b_exp,
    const float* __restrict__ w_rk, const float* __restrict__ w_rv,
    const float* __restrict__ w_dk, const float* __restrict__ w_dv,
    bf16_t* __restrict__ Kr, bf16_t* __restrict__ Vr,
    bf16_t* __restrict__ Kd, bf16_t* __restrict__ Vd)
{
    int tile = blockIdx.x;
    int m    = blockIdx.y;
    int z    = blockIdx.z;
    int b = z >> 1, strm = z & 1;
    const float* W = strm ? (m ? w_dv : w_dk) : (m ? w_rv : w_rk);
    bf16_t* O = (strm ? (m ? Vd : Kd) : (m ? Vr : Kr))
              + ((size_t)b * NTOK + tile * 64) * 64;

    __shared__ float Xs[64][68];
    __shared__ float Ws[64][68];
    int tid = threadIdx.x;
    {
        int r = tid & 63, c0 = tid >> 6;
        stage_x_row(&Xs[r][0], rgb, dep, w_exp, b_exp, b, tile*64 + r, strm, c0, 4);
    }
    int sr = tid >> 4, sc = (tid & 15) * 4;
    #pragma unroll
    for (int rr = 0; rr < 4; ++rr) {
        int r = rr*16 + sr;
        *(float4*)&Ws[r][sc] = *(const float4*)&W[r*64 + sc];
    }
    __syncthreads();

    int ty = tid >> 4, tx = tid & 15;
    float acc[4][4] = {};
    #pragma unroll
    for (int k = 0; k < 64; k += 4) {
        float4 xv[4], wv4[4];
        #pragma unroll
        for (int i = 0; i < 4; ++i) xv[i] = *(const float4*)&Xs[4*ty + i][k];
        #pragma unroll
        for (int j = 0; j < 4; ++j) wv4[j] = *(const float4*)&Ws[tx + 16*j][k];
        #pragma unroll
        for (int i = 0; i < 4; ++i)
            #pragma unroll
            for (int j = 0; j < 4; ++j)
                acc[i][j] += xv[i].x*wv4[j].x + xv[i].y*wv4[j].y + xv[i].z*wv4[j].z + xv[i].w*wv4[j].w;
    }
    #pragma unroll
    for (int i = 0; i < 4; ++i)
        #pragma unroll
        for (int j = 0; j < 4; ++j)
            O[(4*ty + i)*64 + tx + 16*j] = f2bf(acc[i][j]);
}

__global__ __launch_bounds__(256) void attn_all_kernel(
    const float* __restrict__ rgb, const float* __restrict__ dep,
    const float* __restrict__ w_exp, const float* __restrict__ b_exp,
    const float* __restrict__ w_rq, const float* __restrict__ w_dq,
    const bf16_t* __restrict__ Kr, const bf16_t* __restrict__ Vr,
    const bf16_t* __restrict__ Kd, const bf16_t* __restrict__ Vd,
    bf16_t* __restrict__ AOr, bf16_t* __restrict__ AOd)
{
    int qt = blockIdx.x;
    int h  = blockIdx.y;
    int z  = blockIdx.z;
    int b = z >> 1, which = z & 1;
    const float* wq = which ? w_dq : w_rq;
    const bf16_t* K = which ? Kr : Kd;
    const bf16_t* V = which ? Vr : Vd;
    bf16_t* AO      = which ? AOd : AOr;

    __shared__ float Xs[64][68];
    __shared__ float Wqs[8][64];
    __shared__ __align__(16) float Ks[4][64][KVSTRIDE];
    __shared__ __align__(16) float Vs[4][64][KVSTRIDE];

    int tid = threadIdx.x;
    int t = tid & 63;
    int w = tid >> 6;
    int n = qt * 64 + t;

    stage_x_row(&Xs[t][0], rgb, dep, w_exp, b_exp, b, n, which == 0 ? 0 : 1, w, 4);
    if (w == 0) {
        #pragma unroll
        for (int d = 0; d < 8; ++d) Wqs[d][t] = wq[(8*h + d)*64 + t];
    }
    __syncthreads();

    const float sc = 0.35355339059327373f * 1.4426950408889634f;
    float q[8];
    #pragma unroll
    for (int d = 0; d < 8; ++d) {
        float s = 0.f;
        #pragma unroll 8
        for (int c = 0; c < 64; ++c) s += Xs[t][c] * Wqs[d][c];
        q[d] = s * sc;
    }

    float mrun = -INFINITY, l = 0.f;
    float acc[8] = {};

    #pragma unroll 1
    for (int st = 0; st < 9; ++st) {
        __syncthreads();
        {
            size_t g = ((size_t)b * NTOK + (w*576 + st*64 + t)) * 64 + 8 * h;
            *(float4*)&Ks[w][t][0] = ld_bf4(&K[g]);
            *(float4*)&Ks[w][t][4] = ld_bf4(&K[g + 4]);
            *(float4*)&Vs[w][t][0] = ld_bf4(&V[g]);
            *(float4*)&Vs[w][t][4] = ld_bf4(&V[g + 4]);
        }
        __syncthreads();

        for (int g8 = 0; g8 < 8; ++g8) {
            float s[8];
            #pragma unroll
            for (int u = 0; u < 8; ++u) {
                const float4 ka = *(const float4*)&Ks[w][g8*8 + u][0];
                const float4 kb = *(const float4*)&Ks[w][g8*8 + u][4];
                s[u] = q[0]*ka.x + q[1]*ka.y + q[2]*ka.z + q[3]*ka.w
                     + q[4]*kb.x + q[5]*kb.y + q[6]*kb.z + q[7]*kb.w;
            }
            float tm = fmaxf(fmaxf(fmaxf(s[0],s[1]), fmaxf(s[2],s[3])),
                             fmaxf(fmaxf(s[4],s[5]), fmaxf(s[6],s[7])));
            float mn = fmaxf(mrun, tm);
            float alpha = __builtin_amdgcn_exp2f(mrun - mn);
            float ps = 0.f;
            #pragma unroll
            for (int u = 0; u < 8; ++u) { s[u] = __builtin_amdgcn_exp2f(s[u] - mn); ps += s[u]; }
            l = l * alpha + ps;
            #pragma unroll
            for (int d = 0; d < 8; ++d) acc[d] *= alpha;
            #pragma unroll
            for (int u = 0; u < 8; ++u) {
                const float4 va = *(const float4*)&Vs[w][g8*8 + u][0];
                const float4 vb = *(const float4*)&Vs[w][g8*8 + u][4];
                acc[0] += s[u]*va.x; acc[1] += s[u]*va.y; acc[2] += s[u]*va.z; acc[3] += s[u]*va.w;
                acc[4] += s[u]*vb.x; acc[5] += s[u]*vb.y; acc[6] += s[u]*vb.z; acc[7] += s[u]*vb.w;
            }
            mrun = mn;
        }
    }

    float* part = &Xs[0][0];
    __syncthreads();
    {
        float* p = &part[(w*64 + t) * 10];
        p[0] = mrun; p[1] = l;
        #pragma unroll
        for (int d = 0; d < 8; ++d) p[2 + d] = acc[d];
    }
    __syncthreads();
    if (tid < 64) {
        float M = -INFINITY;
        #pragma unroll
        for (int v = 0; v < 4; ++v) M = fmaxf(M, part[(v*64 + t)*10]);
        float L = 0.f, o[8] = {};
        #pragma unroll
        for (int v = 0; v < 4; ++v) {
            const float* p = &part[(v*64 + t)*10];
            float al = __builtin_amdgcn_exp2f(p[0] - M);
            L += p[1] * al;
            #pragma unroll
            for (int d = 0; d < 8; ++d) o[d] += p[2 + d] * al;
        }
        float inv = 1.0f / L;
        uint4 ov;
        ov.x = pack2(o[0]*inv, o[1]*inv);
        ov.y = pack2(o[2]*inv, o[3]*inv);
        ov.z = pack2(o[4]*inv, o[5]*inv);
        ov.w = pack2(o[6]*inv, o[7]*inv);
        *(uint4*)&AO[((size_t)b * NTOK + n) * 64 + 8 * h] = ov;
    }
}

__global__ __launch_bounds__(256) void projcomp_all_kernel(
    const bf16_t* __restrict__ AOr, const bf16_t* __restrict__ AOd,
    const float* __restrict__ w_rp, const float* __restrict__ b_rp,
    const float* __restrict__ w_dp, const float* __restrict__ b_dp,
    const float* __restrict__ w_comp, const float* __restrict__ b_comp,
    float* __restrict__ out)
{
    int tile = blockIdx.x;
    int b    = blockIdx.y;
    __shared__ float A[64][68];
    __shared__ float Bf[64][68];
    __shared__ float Pf[64][68];
    int tid = threadIdx.x;
    int sr = tid >> 4, sc = (tid & 15) * 4;
    int ty = tid >> 4, tx = tid & 15;
    float G[4][4] = {};

    #pragma unroll
    for (int half = 0; half < 2; ++half) {
        const bf16_t* AOx = half ? AOd : AOr;
        const float* Wp   = half ? w_dp : w_rp;
        const float* bp   = half ? b_dp : b_rp;
        #pragma unroll
        for (int rr = 0; rr < 4; ++rr) {
            int r = rr*16 + sr;
            *(float4*)&A[r][sc]  = ld_bf4(&AOx[((size_t)b*NTOK + tile*64 + r)*64 + sc]);
            *(float4*)&Bf[r][sc] = *(const float4*)&Wp[r*64 + sc];
        }
        __syncthreads();
        float acc[4][4] = {};
        #pragma unroll
        for (int k = 0; k < 64; k += 4) {
            float4 xv[4], wv[4];
            #pragma unroll
            for (int i = 0; i < 4; ++i) xv[i] = *(const float4*)&A[4*ty + i][k];
            #pragma unroll
            for (int j = 0; j < 4; ++j) wv[j] = *(const float4*)&Bf[tx + 16*j][k];
            #pragma unroll
            for (int i = 0; i < 4; ++i)
                #pragma unroll
                for (int j = 0; j < 4; ++j)
                    acc[i][j] += xv[i].x*wv[j].x + xv[i].y*wv[j].y + xv[i].z*wv[j].z + xv[i].w*wv[j].w;
        }
        __syncthreads();
        #pragma unroll
        for (int j = 0; j < 4; ++j) {
            float bj = bp[tx + 16*j];
            #pragma unroll
            for (int i = 0; i < 4; ++i)
                Pf[4*ty + i][tx + 16*j] = acc[i][j] + bj;
        }
        #pragma unroll
        for (int rr = 0; rr < 4; ++rr) {
            int r = rr*16 + sr;
            *(float4*)&Bf[r][sc] = *(const float4*)&w_comp[r*128 + half*64 + sc];
        }
        __syncthreads();
        #pragma unroll
        for (int k = 0; k < 64; k += 4) {
            float4 xv[4], wv[4];
            #pragma unroll
            for (int i = 0; i < 4; ++i) xv[i] = *(const float4*)&Pf[4*ty + i][k];
            #pragma unroll
            for (int j = 0; j < 4; ++j) wv[j] = *(const float4*)&Bf[tx + 16*j][k];
            #pragma unroll
            for (int i = 0; i < 4; ++i)
                #pragma unroll
                for (int j = 0; j < 4; ++j)
                    G[i][j] += xv[i].x*wv[j].x + xv[i].y*wv[j].y + xv[i].z*wv[j].z + xv[i].w*wv[j].w;
        }
        __syncthreads();
    }

    #pragma unroll
    for (int j = 0; j < 4; ++j) {
        int o = tx + 16*j;
        float bj = b_comp[o];
        #pragma unroll
        for (int i = 0; i < 4; ++i) {
            int n = tile*64 + 4*ty + i;
            int wi = n / HH, hi = n % HH;
            float x = G[i][j] + bj;
            float g = 0.5f * x * (1.0f + erff(x * 0.70710678118654752f));
            out[((b*C + o)*WW + wi)*HH + hi] = g;
        }
    }
}

// ---------------------------------------------------------------------------
extern "C" void kernel_launch(void* const* d_in, const int* in_sizes, int n_in,
                              void* d_out, int out_size, void* d_ws, size_t ws_size,
                              hipStream_t stream) {
    const float* rgb_fea = (const float*)d_in[0];
    const float* depth   = (const float*)d_in[1];
    const float* w_exp   = (const float*)d_in[2];
    const float* b_exp   = (const float*)d_in[3];
    const float* w_rq    = (const float*)d_in[4];
    const float* w_rk    = (const float*)d_in[5];
    const float* w_rv    = (const float*)d_in[6];
    const float* w_dq    = (const float*)d_in[7];
    const float* w_dk    = (const float*)d_in[8];
    const float* w_dv    = (const float*)d_in[9];
    const float* w_rp    = (const float*)d_in[10];
    const float* b_rp    = (const float*)d_in[11];
    const float* w_dp    = (const float*)d_in[12];
    const float* b_dp    = (const float*)d_in[13];
    const float* w_comp  = (const float*)d_in[14];
    const float* b_comp  = (const float*)d_in[15];
    float* out = (float*)d_out;

    if (ws_size >= 3571968) {
        // Layout:
        //   0         Qb [4][8][2304][8] bf16   (1,179,648)
        //   1,179,648 Kb                        (1,179,648)
        //   2,359,296 VT [4][8][8][2304] bf16   (1,179,648)
        //   3,538,944 W1 (16,384) / 3,555,328 W2 (16,384) / 3,571,712 beff (256)
        char* Wb = (char*)d_ws;
        bf16_t* Qb   = (bf16_t*)Wb;
        bf16_t* Kb   = (bf16_t*)(Wb + 1179648);
        bf16_t* VT   = (bf16_t*)(Wb + 2359296);
        float*  W1   = (float*)(Wb + 3538944);
        float*  W2   = (float*)(Wb + 3555328);
        float*  beff = (float*)(Wb + 3571712);

        qkvprep_kernel<<<dim3(152), dim3(256), 0, stream>>>(
            rgb_fea, depth, w_exp, b_exp,
            w_rq, w_rk, w_rv, w_dq, w_dk, w_dv,
            w_rp, w_dp, w_comp, b_rp, b_dp, b_comp,
            Qb, Kb, VT, W1, W2, beff);
        attnout_kernel<<<dim3(288), dim3(256), 0, stream>>>(
            Qb, Kb, VT, W1, W2, beff, out);
    } else {
        // R9 big path (proven)
        const size_t BUF = (size_t)BATCH * NTOK * 64;
        bf16_t* Kr  = (bf16_t*)d_ws;
        bf16_t* Vr  = Kr + BUF;
        bf16_t* Kd  = Vr + BUF;
        bf16_t* Vd  = Kd + BUF;
        bf16_t* AOr = Vd + BUF;
        bf16_t* AOd = AOr + BUF;
        kv_all_kernel<<<dim3(36, 2, 4), dim3(256), 0, stream>>>(
            rgb_fea, depth, w_exp, b_exp, w_rk, w_rv, w_dk, w_dv, Kr, Vr, Kd, Vd);
        attn_all_kernel<<<dim3(36, 8, 4), dim3(256), 0, stream>>>(
            rgb_fea, depth, w_exp, b_exp, w_rq, w_dq, Kr, Vr, Kd, Vd, AOr, AOd);
        projcomp_all_kernel<<<dim3(36, 2), dim3(256), 0, stream>>>(
            AOr, AOd, w_rp, b_rp, w_dp, b_dp, w_comp, b_comp, out);
    }
}

// Round 6
// 170.002 us; speedup vs baseline: 1.5839x; 1.5839x over previous
//
#include <hip/hip_runtime.h>
#include <math.h>

// R21: R20 (2-dispatch fusion) = 269us, attnout 170us — falsifies dispatch-
// overhead theory. Scaling matches per-wave serial work exactly (R16 4608
// wave-units 52.8us vs R20 1152x4-serial 170us). Cycle arithmetic from
// VALUBusy puts effective clock ~1GHz: burst runs at DVFS floor; every
// kernel is latency-bound on per-wave dependent chains. Fix cycles, not
// structure: revert to R16 4-dispatch shape + (a) attn: 2-deep register
// prefetch of K/V chunks (hide ~200-900cy load under MFMA/exp2 chain);
// (b) qkv: all 3 W matrices register-hoisted upfront (kills 2 serialized
// load stalls), 16-token tiles grid(144,4); (c) outcomp: 16-token tiles
// grid(144,2)=288 blocks. Inner math byte-identical to proven kernels.
#define BATCH 2
#define C 64
#define HH 48
#define WW 48
#define NTOK 2304
#define HEADS 8
#define KVSTRIDE 12

typedef unsigned short bf16_t;
typedef __attribute__((ext_vector_type(8))) short bf16x8;
typedef __attribute__((ext_vector_type(4))) float f32x4;

__device__ __forceinline__ bf16_t f2bf(float f) {
    unsigned int u = __float_as_uint(f);
    u = (u + 0x7fffu + ((u >> 16) & 1u)) >> 16;   // RNE
    return (bf16_t)u;
}
__device__ __forceinline__ unsigned pack2(float a, float b) {
    return (unsigned)f2bf(a) | ((unsigned)f2bf(b) << 16);
}
__device__ __forceinline__ float4 ld_bf4(const bf16_t* p) {
    uint2 v = *(const uint2*)p;
    float4 r;
    r.x = __uint_as_float(v.x << 16); r.y = __uint_as_float(v.x & 0xffff0000u);
    r.z = __uint_as_float(v.y << 16); r.w = __uint_as_float(v.y & 0xffff0000u);
    return r;
}

// Stage one token-row of X (fallback path only).
__device__ __forceinline__ void stage_x_row(
    float* xrow, const float* rgb, const float* dep,
    const float* w_exp, const float* b_exp,
    int b, int n, int strm, int c0, int cstep)
{
    int wi = n / HH, hi = n % HH;
    if (strm == 0) {
        const float* base = rgb + (size_t)b * C * NTOK + (size_t)hi * WW + wi;
        for (int c = c0; c < 64; c += cstep)
            xrow[c] = base[(size_t)c * NTOK];
    } else {
        float cy = 0.5f * hi - 0.25f, cx = 0.5f * wi - 0.25f;
        float fy0 = floorf(cy), fx0 = floorf(cx);
        float fy = cy - fy0, fx = cx - fx0;
        int y0 = max((int)fy0, 0), x0 = max((int)fx0, 0);
        int y1 = min((int)fy0 + 1, 23), x1 = min((int)fx0 + 1, 23);
        const float* dp = dep + b * 576;
        float d00 = dp[y0*24 + x0], d01 = dp[y0*24 + x1];
        float d10 = dp[y1*24 + x0], d11 = dp[y1*24 + x1];
        for (int c = c0; c < 64; c += cstep) {
            float w = w_exp[c], bb = b_exp[c];
            float r00 = fmaxf(w*d00 + bb, 0.f), r01 = fmaxf(w*d01 + bb, 0.f);
            float r10 = fmaxf(w*d10 + bb, 0.f), r11 = fmaxf(w*d11 + bb, 0.f);
            xrow[c] = (1.f-fy)*((1.f-fx)*r00 + fx*r01) + fy*((1.f-fx)*r10 + fx*r11);
        }
    }
}

// ===========================================================================
// MAIN PATH: 4 dispatches (prep, qkv, attn, outcomp).
// ===========================================================================

// Merged xprep (blocks 0..143) + wprep (144..151). Proven in R17.
__global__ __launch_bounds__(256) void prep_kernel(
    const float* __restrict__ rgb, const float* __restrict__ dep,
    const float* __restrict__ w_exp, const float* __restrict__ b_exp,
    const float* __restrict__ w_rp, const float* __restrict__ w_dp,
    const float* __restrict__ w_comp,
    const float* __restrict__ b_rp, const float* __restrict__ b_dp,
    const float* __restrict__ b_comp,
    float* __restrict__ Xt,
    float* __restrict__ W1, float* __restrict__ W2, float* __restrict__ beff)
{
    __shared__ float U[64*68];
    int bid = blockIdx.x;
    int tid = threadIdx.x;

    if (bid < 144) {
        int t = bid >> 2, z = bid & 3;
        int b = z >> 1, strm = z & 1;
        if (strm == 0) {
            const float* src = rgb + (size_t)b * C * NTOK + t * 64;
            #pragma unroll
            for (int p = 0; p < 4; ++p) {
                int idx = tid + p * 256;
                int c = idx >> 4, m4 = (idx & 15) * 4;
                *(float4*)&U[c*65 + m4] = *(const float4*)&src[(size_t)c * NTOK + m4];
            }
            __syncthreads();
            #pragma unroll
            for (int p = 0; p < 4; ++p) {
                int idx = tid + p * 256;
                int row = idx >> 4, l = idx & 15;
                int mi = t * 64 + row;
                int hi = mi / 48, wi = mi % 48;    // rgb memory coords
                int n  = wi * 48 + hi;             // token index
                float4 v;
                v.x = U[(4*l + 0)*65 + row];
                v.y = U[(4*l + 1)*65 + row];
                v.z = U[(4*l + 2)*65 + row];
                v.w = U[(4*l + 3)*65 + row];
                *(float4*)&Xt[((size_t)z * NTOK + n) * 64 + 4*l] = v;
            }
        } else {
            int tok_l = tid >> 2, cq = (tid & 3) * 16;
            int n = t * 64 + tok_l;
            int wi = n / HH, hi = n % HH;
            float cy = 0.5f * hi - 0.25f, cx = 0.5f * wi - 0.25f;
            float fy0 = floorf(cy), fx0 = floorf(cx);
            float fy = cy - fy0, fx = cx - fx0;
            int y0 = max((int)fy0, 0), x0 = max((int)fx0, 0);
            int y1 = min((int)fy0 + 1, 23), x1 = min((int)fx0 + 1, 23);
            const float* dp = dep + b * 576;
            float d00 = dp[y0*24 + x0], d01 = dp[y0*24 + x1];
            float d10 = dp[y1*24 + x0], d11 = dp[y1*24 + x1];
            float* orow = &Xt[((size_t)z * NTOK + n) * 64];
            #pragma unroll
            for (int cc = 0; cc < 16; cc += 4) {
                float4 v;
                #pragma unroll
                for (int j = 0; j < 4; ++j) {
                    int c = cq + cc + j;
                    float w = w_exp[c], bb = b_exp[c];
                    float r00 = fmaxf(w*d00 + bb, 0.f), r01 = fmaxf(w*d01 + bb, 0.f);
                    float r10 = fmaxf(w*d10 + bb, 0.f), r11 = fmaxf(w*d11 + bb, 0.f);
                    ((float*)&v)[j] = (1.f-fy)*((1.f-fx)*r00 + fx*r01)
                                    + fy*((1.f-fx)*r10 + fx*r11);
                }
                *(float4*)&orow[cq + cc] = v;
            }
        }
    } else {
        int idx0 = bid - 144;
        int bx = idx0 & 3, m = idx0 >> 2;
        const float* Wp = m ? w_dp : w_rp;
        float* Wo = m ? W2 : W1;
        int sr = tid >> 4, sc4 = (tid & 15) * 4;
        #pragma unroll
        for (int rr = 0; rr < 4; ++rr) {
            int r = rr*16 + sr;
            *(float4*)&U[r*68 + sc4] = *(const float4*)&Wp[r*64 + sc4];
        }
        __syncthreads();
        int r = tid >> 4;
        int o = bx*16 + r;
        int c4 = (tid & 15) * 4;
        float a0 = 0, a1 = 0, a2 = 0, a3 = 0;
        for (int j = 0; j < 64; ++j) {
            float wc = w_comp[o*128 + m*64 + j];
            float4 wp = *(const float4*)&U[j*68 + c4];
            a0 += wc*wp.x; a1 += wc*wp.y; a2 += wc*wp.z; a3 += wc*wp.w;
        }
        Wo[o*64 + c4]     = a0;
        Wo[o*64 + c4 + 1] = a1;
        Wo[o*64 + c4 + 2] = a2;
        Wo[o*64 + c4 + 3] = a3;
        if (bx == 0 && m == 0 && tid < 64) {
            float s = b_comp[tid];
            for (int j = 0; j < 64; ++j)
                s += w_comp[tid*128 + j] * b_rp[j] + w_comp[tid*128 + 64 + j] * b_dp[j];
            beff[tid] = s;
        }
    }
}

// qkv: grid(144, 4) = 16-token tiles x (b*2+strm). All 3 weight matrices
// register-prefetched UPFRONT (12 independent global loads issue at block
// start) -> phases only pay LDS write + barrier, not global latency.
__global__ __launch_bounds__(256) void qkv_kernel(
    const float* __restrict__ Xt,
    const float* __restrict__ w_rq, const float* __restrict__ w_rk,
    const float* __restrict__ w_rv,
    const float* __restrict__ w_dq, const float* __restrict__ w_dk,
    const float* __restrict__ w_dv,
    bf16_t* __restrict__ Qb, bf16_t* __restrict__ Kb, bf16_t* __restrict__ VT)
{
    int tile = blockIdx.x;           // 0..143 (16 tokens each)
    int z    = blockIdx.y;           // b*2 + strm
    int b = z >> 1, strm = z & 1;
    int sb = strm*2 + b;

    __shared__ float Xs[16][68];
    __shared__ float Ws[64][68];
    int tid = threadIdx.x;
    int sr = tid >> 4, sc = (tid & 15) * 4;

    // Issue ALL weight loads first (independent, overlap with X stage).
    float4 wreg[3][4];
    #pragma unroll
    for (int m = 0; m < 3; ++m) {
        const float* W = strm ? (m == 0 ? w_dq : m == 1 ? w_dk : w_dv)
                              : (m == 0 ? w_rq : m == 1 ? w_rk : w_rv);
        #pragma unroll
        for (int rr = 0; rr < 4; ++rr)
            wreg[m][rr] = *(const float4*)&W[(rr*16 + sr)*64 + sc];
    }
    {
        int row = tid >> 4, c4 = (tid & 15) * 4;
        *(float4*)&Xs[row][c4] =
            *(const float4*)&Xt[((size_t)z*NTOK + tile*16 + row)*64 + c4];
    }

    int ty = tid >> 4, tx = tid & 15;
    #pragma unroll
    for (int m = 0; m < 3; ++m) {
        __syncthreads();   // Xs ready (m=0) / prior GEMM done reading Ws (m>0)
        #pragma unroll
        for (int rr = 0; rr < 4; ++rr)
            *(float4*)&Ws[rr*16 + sr][sc] = wreg[m][rr];
        __syncthreads();

        float acc[4] = {};
        #pragma unroll
        for (int k = 0; k < 64; k += 4) {
            float4 xv = *(const float4*)&Xs[ty][k];
            #pragma unroll
            for (int j = 0; j < 4; ++j) {
                float4 wv = *(const float4*)&Ws[tx + 16*j][k];
                acc[j] += xv.x*wv.x + xv.y*wv.y + xv.z*wv.z + xv.w*wv.w;
            }
        }
        float scale = (m == 0) ? (0.35355339059327373f * 1.4426950408889634f) : 1.0f;
        int n = tile*16 + ty;
        #pragma unroll
        for (int j = 0; j < 4; ++j) {
            int o = tx + 16*j;
            int h = o >> 3, d = o & 7;
            bf16_t v = f2bf(acc[j] * scale);
            if (m == 0)      Qb[(((size_t)sb*8 + h)*NTOK + n)*8 + d] = v;
            else if (m == 1) Kb[(((size_t)sb*8 + h)*NTOK + n)*8 + d] = v;
            else             VT[(((size_t)sb*8 + h)*8 + d)*NTOK + n] = v;
        }
    }
}

// MFMA flash attention with 2-deep K/V register prefetch. grid(36, 8, 4):
// 4 independent waves/block, wave w = qtile blockIdx.x*4+w (16 queries),
// 18 iterations x 128 keys (2 chunks of 64, double-buffered registers):
// chunk cc+1's 6 loads issue BEFORE chunk cc's compute -> load latency
// hides under MFMA/exp2/LDS chain. Math identical to proven R19/R20 body.
__global__ __launch_bounds__(256) void attn_kernel(
    const bf16_t* __restrict__ Qb, const bf16_t* __restrict__ Kb,
    const bf16_t* __restrict__ VT,
    float* __restrict__ AOr, float* __restrict__ AOd)
{
    int h = blockIdx.y;
    int z = blockIdx.z;
    int b = z >> 1, which = z & 1;
    int qsb = which * 2 + b;
    int ksb = (1 - which) * 2 + b;
    const bf16_t* Q  = Qb + ((size_t)qsb * 8 + h) * NTOK * 8;
    const bf16_t* K  = Kb + ((size_t)ksb * 8 + h) * NTOK * 8;
    const bf16_t* Vt = VT + ((size_t)ksb * 8 + h) * 8 * NTOK;  // [d][key]
    float* AO = which ? AOd : AOr;

    __shared__ __align__(16) bf16_t Pls[4][2][16][40];  // 10,240 B
    __shared__ __align__(16) float  Ols[4][16][16];     //  4,096 B

    int tid = threadIdx.x;
    int t = tid & 63, w = tid >> 6;
    int m16 = t & 15, quad = t >> 4;
    int qt = blockIdx.x * 4 + w;       // 0..143
    int n0 = qt * 16;

    const bf16x8 zf = {0,0,0,0,0,0,0,0};
    const bf16x8 onesf = {0x3F80,0x3F80,0x3F80,0x3F80,
                          0x3F80,0x3F80,0x3F80,0x3F80};
    const f32x4 cz = {0.f, 0.f, 0.f, 0.f};
    bf16_t* PA = &Pls[w][0][0][0];
    bf16_t* PB = &Pls[w][1][0][0];

    bf16x8 qf = (quad == 0) ? *(const bf16x8*)&Q[(size_t)(n0 + m16) * 8] : zf;
    f32x4 oacc = cz;

    // one 64-key chunk: S via 4 MFMA, P=exp2 -> bf16 -> per-wave LDS, PV.
    auto compute = [&](bf16x8 kA0, bf16x8 kA1, bf16x8 kB0, bf16x8 kB1,
                       bf16x8 vA, bf16x8 vB) {
        f32x4 sA0 = __builtin_amdgcn_mfma_f32_16x16x32_bf16(qf, kA0, cz, 0, 0, 0);
        f32x4 sA1 = __builtin_amdgcn_mfma_f32_16x16x32_bf16(qf, kA1, cz, 0, 0, 0);
        f32x4 sB0 = __builtin_amdgcn_mfma_f32_16x16x32_bf16(qf, kB0, cz, 0, 0, 0);
        f32x4 sB1 = __builtin_amdgcn_mfma_f32_16x16x32_bf16(qf, kB1, cz, 0, 0, 0);
        #pragma unroll
        for (int q4 = 0; q4 < 4; ++q4) {
            float a0 = __builtin_amdgcn_exp2f(sA0[q4]);
            float a1 = __builtin_amdgcn_exp2f(sA1[q4]);
            float b0 = __builtin_amdgcn_exp2f(sB0[q4]);
            float b1 = __builtin_amdgcn_exp2f(sB1[q4]);
            PA[(quad*4 + q4)*40 + m16]      = (bf16_t)(__float_as_uint(a0) >> 16);
            PA[(quad*4 + q4)*40 + m16 + 16] = (bf16_t)(__float_as_uint(a1) >> 16);
            PB[(quad*4 + q4)*40 + m16]      = (bf16_t)(__float_as_uint(b0) >> 16);
            PB[(quad*4 + q4)*40 + m16 + 16] = (bf16_t)(__float_as_uint(b1) >> 16);
        }
        bf16x8 pfA = *(const bf16x8*)&PA[m16*40 + quad * 8];
        oacc = __builtin_amdgcn_mfma_f32_16x16x32_bf16(pfA, vA, oacc, 0, 0, 0);
        bf16x8 pfB = *(const bf16x8*)&PB[m16*40 + quad * 8];
        oacc = __builtin_amdgcn_mfma_f32_16x16x32_bf16(pfB, vB, oacc, 0, 0, 0);
    };

    // prologue: load chunk 0 into set-0 registers
    bf16x8 c0kA0, c0kA1, c0kB0, c0kB1, c0vA, c0vB;
    {
        c0kA0 = (quad == 0) ? *(const bf16x8*)&K[(size_t)(m16) * 8]      : zf;
        c0kA1 = (quad == 0) ? *(const bf16x8*)&K[(size_t)(16 + m16) * 8] : zf;
        c0kB0 = (quad == 0) ? *(const bf16x8*)&K[(size_t)(32 + m16) * 8] : zf;
        c0kB1 = (quad == 0) ? *(const bf16x8*)&K[(size_t)(48 + m16) * 8] : zf;
        c0vA = (m16 < 8) ? *(const bf16x8*)&Vt[(size_t)m16 * NTOK + quad * 8]
             : (m16 == 8 ? onesf : zf);
        c0vB = (m16 < 8) ? *(const bf16x8*)&Vt[(size_t)m16 * NTOK + 32 + quad * 8]
             : (m16 == 8 ? onesf : zf);
    }

    #pragma unroll 1
    for (int cc = 0; cc < 36; cc += 2) {
        // issue loads for chunk cc+1 (always exists: cc <= 34)
        int k1 = (cc + 1) * 64;
        bf16x8 c1kA0 = (quad == 0) ? *(const bf16x8*)&K[(size_t)(k1 + m16) * 8]      : zf;
        bf16x8 c1kA1 = (quad == 0) ? *(const bf16x8*)&K[(size_t)(k1 + 16 + m16) * 8] : zf;
        bf16x8 c1kB0 = (quad == 0) ? *(const bf16x8*)&K[(size_t)(k1 + 32 + m16) * 8] : zf;
        bf16x8 c1kB1 = (quad == 0) ? *(const bf16x8*)&K[(size_t)(k1 + 48 + m16) * 8] : zf;
        bf16x8 c1vA = (m16 < 8) ? *(const bf16x8*)&Vt[(size_t)m16 * NTOK + k1 + quad * 8]
                    : (m16 == 8 ? onesf : zf);
        bf16x8 c1vB = (m16 < 8) ? *(const bf16x8*)&Vt[(size_t)m16 * NTOK + k1 + 32 + quad * 8]
                    : (m16 == 8 ? onesf : zf);

        compute(c0kA0, c0kA1, c0kB0, c0kB1, c0vA, c0vB);   // chunk cc

        if (cc + 2 < 36) {                // issue loads for chunk cc+2
            int k2 = (cc + 2) * 64;
            c0kA0 = (quad == 0) ? *(const bf16x8*)&K[(size_t)(k2 + m16) * 8]      : zf;
            c0kA1 = (quad == 0) ? *(const bf16x8*)&K[(size_t)(k2 + 16 + m16) * 8] : zf;
            c0kB0 = (quad == 0) ? *(const bf16x8*)&K[(size_t)(k2 + 32 + m16) * 8] : zf;
            c0kB1 = (quad == 0) ? *(const bf16x8*)&K[(size_t)(k2 + 48 + m16) * 8] : zf;
            c0vA = (m16 < 8) ? *(const bf16x8*)&Vt[(size_t)m16 * NTOK + k2 + quad * 8]
                 : (m16 == 8 ? onesf : zf);
            c0vB = (m16 < 8) ? *(const bf16x8*)&Vt[(size_t)m16 * NTOK + k2 + 32 + quad * 8]
                 : (m16 == 8 ? onesf : zf);
        }

        compute(c1kA0, c1kA1, c1kB0, c1kB1, c1vA, c1vB);   // chunk cc+1
    }

    #pragma unroll
    for (int q4 = 0; q4 < 4; ++q4)
        Ols[w][quad*4 + q4][m16] = oacc[q4];
    #pragma unroll
    for (int e = 0; e < 2; ++e) {
        int idx = t * 2 + e;           // 0..127 = 16 q x 8 d
        int qq = idx >> 3, d = idx & 7;
        float val = Ols[w][qq][d] / Ols[w][qq][8];
        AO[((size_t)b * NTOK + n0 + qq) * 64 + 8 * h + d] = val;
    }
}

// Fused 2x K=64 GEMM + beff + GELU + LDS-restage + coalesced store.
// grid(144, 2): 16-token tiles (288 blocks). AO rows already normalized f32.
__global__ __launch_bounds__(256) void outcomp_kernel(
    const float* __restrict__ AOr, const float* __restrict__ AOd,
    const float* __restrict__ W1, const float* __restrict__ W2,
    const float* __restrict__ beff, float* __restrict__ out)
{
    int tile = blockIdx.x;       // 0..143
    int b    = blockIdx.y;
    int n0 = tile * 16;
    __shared__ float Ar[16][68];
    __shared__ float Ad[16][68];
    __shared__ float W1s[64][68];
    __shared__ float W2s[64][68];
    int tid = threadIdx.x;
    {
        int row = tid >> 4, c4 = (tid & 15) * 4;
        size_t base = (size_t)b*NTOK + n0 + row;
        *(float4*)&Ar[row][c4] = *(const float4*)&AOr[base*64 + c4];
        *(float4*)&Ad[row][c4] = *(const float4*)&AOd[base*64 + c4];
    }
    {
        int sr = tid >> 4, sc4 = (tid & 15) * 4;
        #pragma unroll
        for (int rr = 0; rr < 4; ++rr) {
            int r = rr*16 + sr;
            *(float4*)&W1s[r][sc4] = *(const float4*)&W1[r*64 + sc4];
            *(float4*)&W2s[r][sc4] = *(const float4*)&W2[r*64 + sc4];
        }
    }
    __syncthreads();

    int tx = tid & 15, ty = tid >> 4;
    float g[4] = {};
    #pragma unroll
    for (int k = 0; k < 64; k += 4) {
        float4 xr = *(const float4*)&Ar[ty][k];
        float4 xd = *(const float4*)&Ad[ty][k];
        #pragma unroll
        for (int jj = 0; jj < 4; ++jj) {
            float4 w1 = *(const float4*)&W1s[tx + 16*jj][k];
            float4 w2 = *(const float4*)&W2s[tx + 16*jj][k];
            g[jj] += xr.x*w1.x + xr.y*w1.y + xr.z*w1.z + xr.w*w1.w
                   + xd.x*w2.x + xd.y*w2.y + xd.z*w2.z + xd.w*w2.w;
        }
    }

    __syncthreads();                   // done reading W1s/W2s
    float* Gs = &W1s[0][0];            // viewed as [64 o][stride 20]
    #pragma unroll
    for (int jj = 0; jj < 4; ++jj) {
        int o = tx + 16*jj;
        float x = g[jj] + beff[o];
        float gl = 0.5f * x * (1.0f + erff(x * 0.70710678118654752f));
        Gs[o*20 + ty] = gl;
    }
    __syncthreads();
    {
        int o = tid >> 2, s = tid & 3;  // 64 o x 4 float4-segments
        float4 v = *(const float4*)&Gs[o*20 + 4*s];
        *(float4*)&out[((size_t)(b*C + o))*NTOK + n0 + 4*s] = v;
    }
}

// ===========================================================================
// FALLBACK (R9 big path, proven): ws >= 3,538,944 B.
// ===========================================================================
__global__ __launch_bounds__(256) void kv_all_kernel(
    const float* __restrict__ rgb, const float* __restrict__ dep,
    const float* __restrict__ w_exp, const float* __restrict__ b_exp,
    const float* __restrict__ w_rk, const float* __restrict__ w_rv,
    const float* __restrict__ w_dk, const float* __restrict__ w_dv,
    bf16_t* __restrict__ Kr, bf16_t* __restrict__ Vr,
    bf16_t* __restrict__ Kd, bf16_t* __restrict__ Vd)
{
    int tile = blockIdx.x;
    int m    = blockIdx.y;
    int z    = blockIdx.z;
    int b = z >> 1, strm = z & 1;
    const float* W = strm ? (m ? w_dv : w_dk) : (m ? w_rv : w_rk);
    bf16_t* O = (strm ? (m ? Vd : Kd) : (m ? Vr : Kr))
              + ((size_t)b * NTOK + tile * 64) * 64;

    __shared__ float Xs[64][68];
    __shared__ float Ws[64][68];
    int tid = threadIdx.x;
    {
        int r = tid & 63, c0 = tid >> 6;
        stage_x_row(&Xs[r][0], rgb, dep, w_exp, b_exp, b, tile*64 + r, strm, c0, 4);
    }
    int sr = tid >> 4, sc = (tid & 15) * 4;
    #pragma unroll
    for (int rr = 0; rr < 4; ++rr) {
        int r = rr*16 + sr;
        *(float4*)&Ws[r][sc] = *(const float4*)&W[r*64 + sc];
    }
    __syncthreads();

    int ty = tid >> 4, tx = tid & 15;
    float acc[4][4] = {};
    #pragma unroll
    for (int k = 0; k < 64; k += 4) {
        float4 xv[4], wv4[4];
        #pragma unroll
        for (int i = 0; i < 4; ++i) xv[i] = *(const float4*)&Xs[4*ty + i][k];
        #pragma unroll
        for (int j = 0; j < 4; ++j) wv4[j] = *(const float4*)&Ws[tx + 16*j][k];
        #pragma unroll
        for (int i = 0; i < 4; ++i)
            #pragma unroll
            for (int j = 0; j < 4; ++j)
                acc[i][j] += xv[i].x*wv4[j].x + xv[i].y*wv4[j].y + xv[i].z*wv4[j].z + xv[i].w*wv4[j].w;
    }
    #pragma unroll
    for (int i = 0; i < 4; ++i)
        #pragma unroll
        for (int j = 0; j < 4; ++j)
            O[(4*ty + i)*64 + tx + 16*j] = f2bf(acc[i][j]);
}

__global__ __launch_bounds__(256) void attn_all_kernel(
    const float* __restrict__ rgb, const float* __restrict__ dep,
    const float* __restrict__ w_exp, const float* __restrict__ b_exp,
    const float* __restrict__ w_rq, const float* __restrict__ w_dq,
    const bf16_t* __restrict__ Kr, const bf16_t* __restrict__ Vr,
    const bf16_t* __restrict__ Kd, const bf16_t* __restrict__ Vd,
    bf16_t* __restrict__ AOr, bf16_t* __restrict__ AOd)
{
    int qt = blockIdx.x;
    int h  = blockIdx.y;
    int z  = blockIdx.z;
    int b = z >> 1, which = z & 1;
    const float* wq = which ? w_dq : w_rq;
    const bf16_t* K = which ? Kr : Kd;
    const bf16_t* V = which ? Vr : Vd;
    bf16_t* AO      = which ? AOd : AOr;

    __shared__ float Xs[64][68];
    __shared__ float Wqs[8][64];
    __shared__ __align__(16) float Ks[4][64][KVSTRIDE];
    __shared__ __align__(16) float Vs[4][64][KVSTRIDE];

    int tid = threadIdx.x;
    int t = tid & 63;
    int w = tid >> 6;
    int n = qt * 64 + t;

    stage_x_row(&Xs[t][0], rgb, dep, w_exp, b_exp, b, n, which == 0 ? 0 : 1, w, 4);
    if (w == 0) {
        #pragma unroll
        for (int d = 0; d < 8; ++d) Wqs[d][t] = wq[(8*h + d)*64 + t];
    }
    __syncthreads();

    const float sc = 0.35355339059327373f * 1.4426950408889634f;
    float q[8];
    #pragma unroll
    for (int d = 0; d < 8; ++d) {
        float s = 0.f;
        #pragma unroll 8
        for (int c = 0; c < 64; ++c) s += Xs[t][c] * Wqs[d][c];
        q[d] = s * sc;
    }

    float mrun = -INFINITY, l = 0.f;
    float acc[8] = {};

    #pragma unroll 1
    for (int st = 0; st < 9; ++st) {
        __syncthreads();
        {
            size_t g = ((size_t)b * NTOK + (w*576 + st*64 + t)) * 64 + 8 * h;
            *(float4*)&Ks[w][t][0] = ld_bf4(&K[g]);
            *(float4*)&Ks[w][t][4] = ld_bf4(&K[g + 4]);
            *(float4*)&Vs[w][t][0] = ld_bf4(&V[g]);
            *(float4*)&Vs[w][t][4] = ld_bf4(&V[g + 4]);
        }
        __syncthreads();

        for (int g8 = 0; g8 < 8; ++g8) {
            float s[8];
            #pragma unroll
            for (int u = 0; u < 8; ++u) {
                const float4 ka = *(const float4*)&Ks[w][g8*8 + u][0];
                const float4 kb = *(const float4*)&Ks[w][g8*8 + u][4];
                s[u] = q[0]*ka.x + q[1]*ka.y + q[2]*ka.z + q[3]*ka.w
                     + q[4]*kb.x + q[5]*kb.y + q[6]*kb.z + q[7]*kb.w;
            }
            float tm = fmaxf(fmaxf(fmaxf(s[0],s[1]), fmaxf(s[2],s[3])),
                             fmaxf(fmaxf(s[4],s[5]), fmaxf(s[6],s[7])));
            float mn = fmaxf(mrun, tm);
            float alpha = __builtin_amdgcn_exp2f(mrun - mn);
            float ps = 0.f;
            #pragma unroll
            for (int u = 0; u < 8; ++u) { s[u] = __builtin_amdgcn_exp2f(s[u] - mn); ps += s[u]; }
            l = l * alpha + ps;
            #pragma unroll
            for (int d = 0; d < 8; ++d) acc[d] *= alpha;
            #pragma unroll
            for (int u = 0; u < 8; ++u) {
                const float4 va = *(const float4*)&Vs[w][g8*8 + u][0];
                const float4 vb = *(const float4*)&Vs[w][g8*8 + u][4];
                acc[0] += s[u]*va.x; acc[1] += s[u]*va.y; acc[2] += s[u]*va.z; acc[3] += s[u]*va.w;
                acc[4] += s[u]*vb.x; acc[5] += s[u]*vb.y; acc[6] += s[u]*vb.z; acc[7] += s[u]*vb.w;
            }
            mrun = mn;
        }
    }

    float* part = &Xs[0][0];
    __syncthreads();
    {
        float* p = &part[(w*64 + t) * 10];
        p[0] = mrun; p[1] = l;
        #pragma unroll
        for (int d = 0; d < 8; ++d) p[2 + d] = acc[d];
    }
    __syncthreads();
    if (tid < 64) {
        float M = -INFINITY;
        #pragma unroll
        for (int v = 0; v < 4; ++v) M = fmaxf(M, part[(v*64 + t)*10]);
        float L = 0.f, o[8] = {};
        #pragma unroll
        for (int v = 0; v < 4; ++v) {
            const float* p = &part[(v*64 + t)*10];
            float al = __builtin_amdgcn_exp2f(p[0] - M);
            L += p[1] * al;
            #pragma unroll
            for (int d = 0; d < 8; ++d) o[d] += p[2 + d] * al;
        }
        float inv = 1.0f / L;
        uint4 ov;
        ov.x = pack2(o[0]*inv, o[1]*inv);
        ov.y = pack2(o[2]*inv, o[3]*inv);
        ov.z = pack2(o[4]*inv, o[5]*inv);
        ov.w = pack2(o[6]*inv, o[7]*inv);
        *(uint4*)&AO[((size_t)b * NTOK + n) * 64 + 8 * h] = ov;
    }
}

__global__ __launch_bounds__(256) void projcomp_all_kernel(
    const bf16_t* __restrict__ AOr, const bf16_t* __restrict__ AOd,
    const float* __restrict__ w_rp, const float* __restrict__ b_rp,
    const float* __restrict__ w_dp, const float* __restrict__ b_dp,
    const float* __restrict__ w_comp, const float* __restrict__ b_comp,
    float* __restrict__ out)
{
    int tile = blockIdx.x;
    int b    = blockIdx.y;
    __shared__ float A[64][68];
    __shared__ float Bf[64][68];
    __shared__ float Pf[64][68];
    int tid = threadIdx.x;
    int sr = tid >> 4, sc = (tid & 15) * 4;
    int ty = tid >> 4, tx = tid & 15;
    float G[4][4] = {};

    #pragma unroll
    for (int half = 0; half < 2; ++half) {
        const bf16_t* AOx = half ? AOd : AOr;
        const float* Wp   = half ? w_dp : w_rp;
        const float* bp   = half ? b_dp : b_rp;
        #pragma unroll
        for (int rr = 0; rr < 4; ++rr) {
            int r = rr*16 + sr;
            *(float4*)&A[r][sc]  = ld_bf4(&AOx[((size_t)b*NTOK + tile*64 + r)*64 + sc]);
            *(float4*)&Bf[r][sc] = *(const float4*)&Wp[r*64 + sc];
        }
        __syncthreads();
        float acc[4][4] = {};
        #pragma unroll
        for (int k = 0; k < 64; k += 4) {
            float4 xv[4], wv[4];
            #pragma unroll
            for (int i = 0; i < 4; ++i) xv[i] = *(const float4*)&A[4*ty + i][k];
            #pragma unroll
            for (int j = 0; j < 4; ++j) wv[j] = *(const float4*)&Bf[tx + 16*j][k];
            #pragma unroll
            for (int i = 0; i < 4; ++i)
                #pragma unroll
                for (int j = 0; j < 4; ++j)
                    acc[i][j] += xv[i].x*wv[j].x + xv[i].y*wv[j].y + xv[i].z*wv[j].z + xv[i].w*wv[j].w;
        }
        __syncthreads();
        #pragma unroll
        for (int j = 0; j < 4; ++j) {
            float bj = bp[tx + 16*j];
            #pragma unroll
            for (int i = 0; i < 4; ++i)
                Pf[4*ty + i][tx + 16*j] = acc[i][j] + bj;
        }
        #pragma unroll
        for (int rr = 0; rr < 4; ++rr) {
            int r = rr*16 + sr;
            *(float4*)&Bf[r][sc] = *(const float4*)&w_comp[r*128 + half*64 + sc];
        }
        __syncthreads();
        #pragma unroll
        for (int k = 0; k < 64; k += 4) {
            float4 xv[4], wv[4];
            #pragma unroll
            for (int i = 0; i < 4; ++i) xv[i] = *(const float4*)&Pf[4*ty + i][k];
            #pragma unroll
            for (int j = 0; j < 4; ++j) wv[j] = *(const float4*)&Bf[tx + 16*j][k];
            #pragma unroll
            for (int i = 0; i < 4; ++i)
                #pragma unroll
                for (int j = 0; j < 4; ++j)
                    G[i][j] += xv[i].x*wv[j].x + xv[i].y*wv[j].y + xv[i].z*wv[j].z + xv[i].w*wv[j].w;
        }
        __syncthreads();
    }

    #pragma unroll
    for (int j = 0; j < 4; ++j) {
        int o = tx + 16*j;
        float bj = b_comp[o];
        #pragma unroll
        for (int i = 0; i < 4; ++i) {
            int n = tile*64 + 4*ty + i;
            int wi = n / HH, hi = n % HH;
            float x = G[i][j] + bj;
            float g = 0.5f * x * (1.0f + erff(x * 0.70710678118654752f));
            out[((b*C + o)*WW + wi)*HH + hi] = g;
        }
    }
}

// ---------------------------------------------------------------------------
extern "C" void kernel_launch(void* const* d_in, const int* in_sizes, int n_in,
                              void* d_out, int out_size, void* d_ws, size_t ws_size,
                              hipStream_t stream) {
    const float* rgb_fea = (const float*)d_in[0];
    const float* depth   = (const float*)d_in[1];
    const float* w_exp   = (const float*)d_in[2];
    const float* b_exp   = (const float*)d_in[3];
    const float* w_rq    = (const float*)d_in[4];
    const float* w_rk    = (const float*)d_in[5];
    const float* w_rv    = (const float*)d_in[6];
    const float* w_dq    = (const float*)d_in[7];
    const float* w_dk    = (const float*)d_in[8];
    const float* w_dv    = (const float*)d_in[9];
    const float* w_rp    = (const float*)d_in[10];
    const float* b_rp    = (const float*)d_in[11];
    const float* w_dp    = (const float*)d_in[12];
    const float* b_dp    = (const float*)d_in[13];
    const float* w_comp  = (const float*)d_in[14];
    const float* b_comp  = (const float*)d_in[15];
    float* out = (float*)d_out;

    if (ws_size >= 5931264) {
        // Layout (same as R16 T1):
        //   0        Qb [4][8][2304][8] bf16   (1,179,648)
        //   1179648  Kb                        (1,179,648)
        //   2359296  VT [4][8][8][2304] bf16   (1,179,648)
        //   3538944  XtAO: Xt [4][2304][64] f32 == AOr+AOd (2,359,296)
        //   5898240  W1 / 5914624 W2 / 5931008 beff
        char* Wb = (char*)d_ws;
        bf16_t* Qb   = (bf16_t*)Wb;
        bf16_t* Kb   = (bf16_t*)(Wb + 1179648);
        bf16_t* VT   = (bf16_t*)(Wb + 2359296);
        float*  XtAO = (float*)(Wb + 3538944);
        float*  AOr  = XtAO;
        float*  AOd  = XtAO + 294912;
        float*  W1   = (float*)(Wb + 5898240);
        float*  W2   = (float*)(Wb + 5914624);
        float*  beff = (float*)(Wb + 5931008);
        float*  Xt   = XtAO;   // dead after qkv; attn overwrites as AO

        prep_kernel<<<dim3(152), dim3(256), 0, stream>>>(
            rgb_fea, depth, w_exp, b_exp, w_rp, w_dp, w_comp,
            b_rp, b_dp, b_comp, Xt, W1, W2, beff);
        qkv_kernel<<<dim3(144, 4), dim3(256), 0, stream>>>(
            Xt, w_rq, w_rk, w_rv, w_dq, w_dk, w_dv, Qb, Kb, VT);
        attn_kernel<<<dim3(36, 8, 4), dim3(256), 0, stream>>>(
            Qb, Kb, VT, AOr, AOd);
        outcomp_kernel<<<dim3(144, 2), dim3(256), 0, stream>>>(
            AOr, AOd, W1, W2, beff, out);
    } else {
        // R9 big path (proven)
        const size_t BUF = (size_t)BATCH * NTOK * 64;
        bf16_t* Kr  = (bf16_t*)d_ws;
        bf16_t* Vr  = Kr + BUF;
        bf16_t* Kd  = Vr + BUF;
        bf16_t* Vd  = Kd + BUF;
        bf16_t* AOr = Vd + BUF;
        bf16_t* AOd = AOr + BUF;
        kv_all_kernel<<<dim3(36, 2, 4), dim3(256), 0, stream>>>(
            rgb_fea, depth, w_exp, b_exp, w_rk, w_rv, w_dk, w_dv, Kr, Vr, Kd, Vd);
        attn_all_kernel<<<dim3(36, 8, 4), dim3(256), 0, stream>>>(
            rgb_fea, depth, w_exp, b_exp, w_rq, w_dq, Kr, Vr, Kd, Vd, AOr, AOd);
        projcomp_all_kernel<<<dim3(36, 2), dim3(256), 0, stream>>>(
            AOr, AOd, w_rp, b_rp, w_dp, b_dp, w_comp, b_comp, out);
    }
}

// Round 7
// 166.389 us; speedup vs baseline: 1.6183x; 1.0217x over previous
//
#include <hip/hip_runtime.h>
#include <math.h>

// R22: R21=170us (best). attn audit: per 32-key chunk each lane does 8
// scalar u16 LDS stores + 1 b128 read for the P transpose; at 18 waves/CU
// x 72 chunks the per-CU LDS issue port (~5cy/op) accounts for ~the whole
// 58us dispatch -> LDS-ISSUE-bound (explains why occupancy (R17) and
// prefetch (R21) both failed; VALUBusy 33%, MfmaUtil 10%, 1.4M conflicts).
// Fix: swap QK^T operands — S^T = mfma(kf, qf) puts 4 CONSECUTIVE keys of
// one query in each lane -> exp2 results pack into ONE b64 store (4 bf16).
// DS ops per chunk: 9 -> 3. A/B frags of 16x16x32 have identical lane
// layouts so the swap is free; read side + all math bit-identical.
// Cadence reverted to R16's plain 72x32-key loop (measured faster than
// prefetch). prep/qkv/outcomp (R21, proven) untouched.
#define BATCH 2
#define C 64
#define HH 48
#define WW 48
#define NTOK 2304
#define HEADS 8
#define KVSTRIDE 12

typedef unsigned short bf16_t;
typedef __attribute__((ext_vector_type(8))) short bf16x8;
typedef __attribute__((ext_vector_type(4))) short bf16x4;
typedef __attribute__((ext_vector_type(4))) float f32x4;

__device__ __forceinline__ bf16_t f2bf(float f) {
    unsigned int u = __float_as_uint(f);
    u = (u + 0x7fffu + ((u >> 16) & 1u)) >> 16;   // RNE
    return (bf16_t)u;
}
__device__ __forceinline__ unsigned pack2(float a, float b) {
    return (unsigned)f2bf(a) | ((unsigned)f2bf(b) << 16);
}
__device__ __forceinline__ float4 ld_bf4(const bf16_t* p) {
    uint2 v = *(const uint2*)p;
    float4 r;
    r.x = __uint_as_float(v.x << 16); r.y = __uint_as_float(v.x & 0xffff0000u);
    r.z = __uint_as_float(v.y << 16); r.w = __uint_as_float(v.y & 0xffff0000u);
    return r;
}

// Stage one token-row of X (fallback path only).
__device__ __forceinline__ void stage_x_row(
    float* xrow, const float* rgb, const float* dep,
    const float* w_exp, const float* b_exp,
    int b, int n, int strm, int c0, int cstep)
{
    int wi = n / HH, hi = n % HH;
    if (strm == 0) {
        const float* base = rgb + (size_t)b * C * NTOK + (size_t)hi * WW + wi;
        for (int c = c0; c < 64; c += cstep)
            xrow[c] = base[(size_t)c * NTOK];
    } else {
        float cy = 0.5f * hi - 0.25f, cx = 0.5f * wi - 0.25f;
        float fy0 = floorf(cy), fx0 = floorf(cx);
        float fy = cy - fy0, fx = cx - fx0;
        int y0 = max((int)fy0, 0), x0 = max((int)fx0, 0);
        int y1 = min((int)fy0 + 1, 23), x1 = min((int)fx0 + 1, 23);
        const float* dp = dep + b * 576;
        float d00 = dp[y0*24 + x0], d01 = dp[y0*24 + x1];
        float d10 = dp[y1*24 + x0], d11 = dp[y1*24 + x1];
        for (int c = c0; c < 64; c += cstep) {
            float w = w_exp[c], bb = b_exp[c];
            float r00 = fmaxf(w*d00 + bb, 0.f), r01 = fmaxf(w*d01 + bb, 0.f);
            float r10 = fmaxf(w*d10 + bb, 0.f), r11 = fmaxf(w*d11 + bb, 0.f);
            xrow[c] = (1.f-fy)*((1.f-fx)*r00 + fx*r01) + fy*((1.f-fx)*r10 + fx*r11);
        }
    }
}

// ===========================================================================
// MAIN PATH: 4 dispatches (prep, qkv, attn, outcomp).
// ===========================================================================

// Merged xprep (blocks 0..143) + wprep (144..151). Proven in R17/R21.
__global__ __launch_bounds__(256) void prep_kernel(
    const float* __restrict__ rgb, const float* __restrict__ dep,
    const float* __restrict__ w_exp, const float* __restrict__ b_exp,
    const float* __restrict__ w_rp, const float* __restrict__ w_dp,
    const float* __restrict__ w_comp,
    const float* __restrict__ b_rp, const float* __restrict__ b_dp,
    const float* __restrict__ b_comp,
    float* __restrict__ Xt,
    float* __restrict__ W1, float* __restrict__ W2, float* __restrict__ beff)
{
    __shared__ float U[64*68];
    int bid = blockIdx.x;
    int tid = threadIdx.x;

    if (bid < 144) {
        int t = bid >> 2, z = bid & 3;
        int b = z >> 1, strm = z & 1;
        if (strm == 0) {
            const float* src = rgb + (size_t)b * C * NTOK + t * 64;
            #pragma unroll
            for (int p = 0; p < 4; ++p) {
                int idx = tid + p * 256;
                int c = idx >> 4, m4 = (idx & 15) * 4;
                *(float4*)&U[c*65 + m4] = *(const float4*)&src[(size_t)c * NTOK + m4];
            }
            __syncthreads();
            #pragma unroll
            for (int p = 0; p < 4; ++p) {
                int idx = tid + p * 256;
                int row = idx >> 4, l = idx & 15;
                int mi = t * 64 + row;
                int hi = mi / 48, wi = mi % 48;    // rgb memory coords
                int n  = wi * 48 + hi;             // token index
                float4 v;
                v.x = U[(4*l + 0)*65 + row];
                v.y = U[(4*l + 1)*65 + row];
                v.z = U[(4*l + 2)*65 + row];
                v.w = U[(4*l + 3)*65 + row];
                *(float4*)&Xt[((size_t)z * NTOK + n) * 64 + 4*l] = v;
            }
        } else {
            int tok_l = tid >> 2, cq = (tid & 3) * 16;
            int n = t * 64 + tok_l;
            int wi = n / HH, hi = n % HH;
            float cy = 0.5f * hi - 0.25f, cx = 0.5f * wi - 0.25f;
            float fy0 = floorf(cy), fx0 = floorf(cx);
            float fy = cy - fy0, fx = cx - fx0;
            int y0 = max((int)fy0, 0), x0 = max((int)fx0, 0);
            int y1 = min((int)fy0 + 1, 23), x1 = min((int)fx0 + 1, 23);
            const float* dp = dep + b * 576;
            float d00 = dp[y0*24 + x0], d01 = dp[y0*24 + x1];
            float d10 = dp[y1*24 + x0], d11 = dp[y1*24 + x1];
            float* orow = &Xt[((size_t)z * NTOK + n) * 64];
            #pragma unroll
            for (int cc = 0; cc < 16; cc += 4) {
                float4 v;
                #pragma unroll
                for (int j = 0; j < 4; ++j) {
                    int c = cq + cc + j;
                    float w = w_exp[c], bb = b_exp[c];
                    float r00 = fmaxf(w*d00 + bb, 0.f), r01 = fmaxf(w*d01 + bb, 0.f);
                    float r10 = fmaxf(w*d10 + bb, 0.f), r11 = fmaxf(w*d11 + bb, 0.f);
                    ((float*)&v)[j] = (1.f-fy)*((1.f-fx)*r00 + fx*r01)
                                    + fy*((1.f-fx)*r10 + fx*r11);
                }
                *(float4*)&orow[cq + cc] = v;
            }
        }
    } else {
        int idx0 = bid - 144;
        int bx = idx0 & 3, m = idx0 >> 2;
        const float* Wp = m ? w_dp : w_rp;
        float* Wo = m ? W2 : W1;
        int sr = tid >> 4, sc4 = (tid & 15) * 4;
        #pragma unroll
        for (int rr = 0; rr < 4; ++rr) {
            int r = rr*16 + sr;
            *(float4*)&U[r*68 + sc4] = *(const float4*)&Wp[r*64 + sc4];
        }
        __syncthreads();
        int r = tid >> 4;
        int o = bx*16 + r;
        int c4 = (tid & 15) * 4;
        float a0 = 0, a1 = 0, a2 = 0, a3 = 0;
        for (int j = 0; j < 64; ++j) {
            float wc = w_comp[o*128 + m*64 + j];
            float4 wp = *(const float4*)&U[j*68 + c4];
            a0 += wc*wp.x; a1 += wc*wp.y; a2 += wc*wp.z; a3 += wc*wp.w;
        }
        Wo[o*64 + c4]     = a0;
        Wo[o*64 + c4 + 1] = a1;
        Wo[o*64 + c4 + 2] = a2;
        Wo[o*64 + c4 + 3] = a3;
        if (bx == 0 && m == 0 && tid < 64) {
            float s = b_comp[tid];
            for (int j = 0; j < 64; ++j)
                s += w_comp[tid*128 + j] * b_rp[j] + w_comp[tid*128 + 64 + j] * b_dp[j];
            beff[tid] = s;
        }
    }
}

// qkv: grid(144, 4) = 16-token tiles x (b*2+strm). All 3 weight matrices
// register-prefetched UPFRONT. Proven in R21.
__global__ __launch_bounds__(256) void qkv_kernel(
    const float* __restrict__ Xt,
    const float* __restrict__ w_rq, const float* __restrict__ w_rk,
    const float* __restrict__ w_rv,
    const float* __restrict__ w_dq, const float* __restrict__ w_dk,
    const float* __restrict__ w_dv,
    bf16_t* __restrict__ Qb, bf16_t* __restrict__ Kb, bf16_t* __restrict__ VT)
{
    int tile = blockIdx.x;           // 0..143 (16 tokens each)
    int z    = blockIdx.y;           // b*2 + strm
    int b = z >> 1, strm = z & 1;
    int sb = strm*2 + b;

    __shared__ float Xs[16][68];
    __shared__ float Ws[64][68];
    int tid = threadIdx.x;
    int sr = tid >> 4, sc = (tid & 15) * 4;

    // Issue ALL weight loads first (independent, overlap with X stage).
    float4 wreg[3][4];
    #pragma unroll
    for (int m = 0; m < 3; ++m) {
        const float* W = strm ? (m == 0 ? w_dq : m == 1 ? w_dk : w_dv)
                              : (m == 0 ? w_rq : m == 1 ? w_rk : w_rv);
        #pragma unroll
        for (int rr = 0; rr < 4; ++rr)
            wreg[m][rr] = *(const float4*)&W[(rr*16 + sr)*64 + sc];
    }
    {
        int row = tid >> 4, c4 = (tid & 15) * 4;
        *(float4*)&Xs[row][c4] =
            *(const float4*)&Xt[((size_t)z*NTOK + tile*16 + row)*64 + c4];
    }

    int ty = tid >> 4, tx = tid & 15;
    #pragma unroll
    for (int m = 0; m < 3; ++m) {
        __syncthreads();   // Xs ready (m=0) / prior GEMM done reading Ws (m>0)
        #pragma unroll
        for (int rr = 0; rr < 4; ++rr)
            *(float4*)&Ws[rr*16 + sr][sc] = wreg[m][rr];
        __syncthreads();

        float acc[4] = {};
        #pragma unroll
        for (int k = 0; k < 64; k += 4) {
            float4 xv = *(const float4*)&Xs[ty][k];
            #pragma unroll
            for (int j = 0; j < 4; ++j) {
                float4 wv = *(const float4*)&Ws[tx + 16*j][k];
                acc[j] += xv.x*wv.x + xv.y*wv.y + xv.z*wv.z + xv.w*wv.w;
            }
        }
        float scale = (m == 0) ? (0.35355339059327373f * 1.4426950408889634f) : 1.0f;
        int n = tile*16 + ty;
        #pragma unroll
        for (int j = 0; j < 4; ++j) {
            int o = tx + 16*j;
            int h = o >> 3, d = o & 7;
            bf16_t v = f2bf(acc[j] * scale);
            if (m == 0)      Qb[(((size_t)sb*8 + h)*NTOK + n)*8 + d] = v;
            else if (m == 1) Kb[(((size_t)sb*8 + h)*NTOK + n)*8 + d] = v;
            else             VT[(((size_t)sb*8 + h)*8 + d)*NTOK + n] = v;
        }
    }
}

// MFMA flash attention, swapped-operand S^T + packed b64 P stores.
// grid(36, 8, 4); 4 independent waves; wave w = qtile blockIdx.x*4+w.
// Per 32-key chunk: S^T = mfma(kf,qf) -> lane holds S[key=quad*4+r][q=m16]
// -> exp2 -> ONE b64 store per 16-key group (cols quad*4..+3 of row m16).
// Read side (b128 A-frag at [m16][quad*8]) and ALL values bit-identical
// to the proven R16 kernel; only store width changed (8 u16 -> 2 b64).
__global__ __launch_bounds__(256) void attn_kernel(
    const bf16_t* __restrict__ Qb, const bf16_t* __restrict__ Kb,
    const bf16_t* __restrict__ VT,
    float* __restrict__ AOr, float* __restrict__ AOd)
{
    int h = blockIdx.y;
    int z = blockIdx.z;
    int b = z >> 1, which = z & 1;
    int qsb = which * 2 + b;
    int ksb = (1 - which) * 2 + b;
    const bf16_t* Q  = Qb + ((size_t)qsb * 8 + h) * NTOK * 8;
    const bf16_t* K  = Kb + ((size_t)ksb * 8 + h) * NTOK * 8;
    const bf16_t* Vt = VT + ((size_t)ksb * 8 + h) * 8 * NTOK;  // [d][key]
    float* AO = which ? AOd : AOr;

    __shared__ __align__(16) bf16_t Pls[4][16][40];  // 5 KB, rows 80 B
    __shared__ __align__(16) float  Ols[4][16][16];  // 4 KB

    int tid = threadIdx.x;
    int t = tid & 63, w = tid >> 6;
    int m16 = t & 15, quad = t >> 4;
    int qt = blockIdx.x * 4 + w;       // 0..143
    int n0 = qt * 16;

    const bf16x8 zf = {0,0,0,0,0,0,0,0};
    const bf16x8 onesf = {0x3F80,0x3F80,0x3F80,0x3F80,
                          0x3F80,0x3F80,0x3F80,0x3F80};
    const f32x4 cz = {0.f, 0.f, 0.f, 0.f};

    // Q fragment: row m16 = query, dims 0-7 in quad 0 (quads 1-3 zero).
    bf16x8 qf = (quad == 0) ? *(const bf16x8*)&Q[(size_t)(n0 + m16) * 8] : zf;

    f32x4 oacc = cz;

    #pragma unroll 1
    for (int ck = 0; ck < 72; ++ck) {
        int k0 = ck * 32;
        bf16x8 kf0 = (quad == 0) ? *(const bf16x8*)&K[(size_t)(k0 + m16) * 8]      : zf;
        bf16x8 kf1 = (quad == 0) ? *(const bf16x8*)&K[(size_t)(k0 + 16 + m16) * 8] : zf;
        bf16x8 vf = (m16 < 8) ? *(const bf16x8*)&Vt[(size_t)m16 * NTOK + k0 + quad * 8]
                  : (m16 == 8 ? onesf : zf);

        // SWAPPED operands: S^T[key][query]. A/B frags have identical lane
        // layouts for 16x16x32, so kf/qf slot-swap is layout-exact.
        f32x4 s0 = __builtin_amdgcn_mfma_f32_16x16x32_bf16(kf0, qf, cz, 0, 0, 0);
        f32x4 s1 = __builtin_amdgcn_mfma_f32_16x16x32_bf16(kf1, qf, cz, 0, 0, 0);

        // lane (quad,m16): s0[r] = S[key=k0+quad*4+r][q=m16]
        //                  s1[r] = S[key=k0+16+quad*4+r][q=m16]
        bf16x4 pA, pB;
        #pragma unroll
        for (int r = 0; r < 4; ++r) {
            float p0 = __builtin_amdgcn_exp2f(s0[r]);
            float p1 = __builtin_amdgcn_exp2f(s1[r]);
            pA[r] = (short)(__float_as_uint(p0) >> 16);
            pB[r] = (short)(__float_as_uint(p1) >> 16);
        }
        *(bf16x4*)&Pls[w][m16][quad * 4]      = pA;   // keys quad*4..+3
        *(bf16x4*)&Pls[w][m16][16 + quad * 4] = pB;   // keys 16+quad*4..+3

        bf16x8 pf = *(const bf16x8*)&Pls[w][m16][quad * 8];
        oacc = __builtin_amdgcn_mfma_f32_16x16x32_bf16(pf, vf, oacc, 0, 0, 0);
    }

    #pragma unroll
    for (int r = 0; r < 4; ++r)
        Ols[w][quad*4 + r][m16] = oacc[r];
    #pragma unroll
    for (int e = 0; e < 2; ++e) {
        int idx = t * 2 + e;           // 0..127 = 16 q x 8 d
        int qq = idx >> 3, d = idx & 7;
        float val = Ols[w][qq][d] / Ols[w][qq][8];
        AO[((size_t)b * NTOK + n0 + qq) * 64 + 8 * h + d] = val;
    }
}

// Fused 2x K=64 GEMM + beff + GELU + LDS-restage + coalesced store.
// grid(144, 2): 16-token tiles (288 blocks). Proven in R21.
__global__ __launch_bounds__(256) void outcomp_kernel(
    const float* __restrict__ AOr, const float* __restrict__ AOd,
    const float* __restrict__ W1, const float* __restrict__ W2,
    const float* __restrict__ beff, float* __restrict__ out)
{
    int tile = blockIdx.x;       // 0..143
    int b    = blockIdx.y;
    int n0 = tile * 16;
    __shared__ float Ar[16][68];
    __shared__ float Ad[16][68];
    __shared__ float W1s[64][68];
    __shared__ float W2s[64][68];
    int tid = threadIdx.x;
    {
        int row = tid >> 4, c4 = (tid & 15) * 4;
        size_t base = (size_t)b*NTOK + n0 + row;
        *(float4*)&Ar[row][c4] = *(const float4*)&AOr[base*64 + c4];
        *(float4*)&Ad[row][c4] = *(const float4*)&AOd[base*64 + c4];
    }
    {
        int sr = tid >> 4, sc4 = (tid & 15) * 4;
        #pragma unroll
        for (int rr = 0; rr < 4; ++rr) {
            int r = rr*16 + sr;
            *(float4*)&W1s[r][sc4] = *(const float4*)&W1[r*64 + sc4];
            *(float4*)&W2s[r][sc4] = *(const float4*)&W2[r*64 + sc4];
        }
    }
    __syncthreads();

    int tx = tid & 15, ty = tid >> 4;
    float g[4] = {};
    #pragma unroll
    for (int k = 0; k < 64; k += 4) {
        float4 xr = *(const float4*)&Ar[ty][k];
        float4 xd = *(const float4*)&Ad[ty][k];
        #pragma unroll
        for (int jj = 0; jj < 4; ++jj) {
            float4 w1 = *(const float4*)&W1s[tx + 16*jj][k];
            float4 w2 = *(const float4*)&W2s[tx + 16*jj][k];
            g[jj] += xr.x*w1.x + xr.y*w1.y + xr.z*w1.z + xr.w*w1.w
                   + xd.x*w2.x + xd.y*w2.y + xd.z*w2.z + xd.w*w2.w;
        }
    }

    __syncthreads();                   // done reading W1s/W2s
    float* Gs = &W1s[0][0];            // viewed as [64 o][stride 20]
    #pragma unroll
    for (int jj = 0; jj < 4; ++jj) {
        int o = tx + 16*jj;
        float x = g[jj] + beff[o];
        float gl = 0.5f * x * (1.0f + erff(x * 0.70710678118654752f));
        Gs[o*20 + ty] = gl;
    }
    __syncthreads();
    {
        int o = tid >> 2, s = tid & 3;  // 64 o x 4 float4-segments
        float4 v = *(const float4*)&Gs[o*20 + 4*s];
        *(float4*)&out[((size_t)(b*C + o))*NTOK + n0 + 4*s] = v;
    }
}

// ===========================================================================
// FALLBACK (R9 big path, proven): ws >= 3,538,944 B.
// ===========================================================================
__global__ __launch_bounds__(256) void kv_all_kernel(
    const float* __restrict__ rgb, const float* __restrict__ dep,
    const float* __restrict__ w_exp, const float* __restrict__ b_exp,
    const float* __restrict__ w_rk, const float* __restrict__ w_rv,
    const float* __restrict__ w_dk, const float* __restrict__ w_dv,
    bf16_t* __restrict__ Kr, bf16_t* __restrict__ Vr,
    bf16_t* __restrict__ Kd, bf16_t* __restrict__ Vd)
{
    int tile = blockIdx.x;
    int m    = blockIdx.y;
    int z    = blockIdx.z;
    int b = z >> 1, strm = z & 1;
    const float* W = strm ? (m ? w_dv : w_dk) : (m ? w_rv : w_rk);
    bf16_t* O = (strm ? (m ? Vd : Kd) : (m ? Vr : Kr))
              + ((size_t)b * NTOK + tile * 64) * 64;

    __shared__ float Xs[64][68];
    __shared__ float Ws[64][68];
    int tid = threadIdx.x;
    {
        int r = tid & 63, c0 = tid >> 6;
        stage_x_row(&Xs[r][0], rgb, dep, w_exp, b_exp, b, tile*64 + r, strm, c0, 4);
    }
    int sr = tid >> 4, sc = (tid & 15) * 4;
    #pragma unroll
    for (int rr = 0; rr < 4; ++rr) {
        int r = rr*16 + sr;
        *(float4*)&Ws[r][sc] = *(const float4*)&W[r*64 + sc];
    }
    __syncthreads();

    int ty = tid >> 4, tx = tid & 15;
    float acc[4][4] = {};
    #pragma unroll
    for (int k = 0; k < 64; k += 4) {
        float4 xv[4], wv4[4];
        #pragma unroll
        for (int i = 0; i < 4; ++i) xv[i] = *(const float4*)&Xs[4*ty + i][k];
        #pragma unroll
        for (int j = 0; j < 4; ++j) wv4[j] = *(const float4*)&Ws[tx + 16*j][k];
        #pragma unroll
        for (int i = 0; i < 4; ++i)
            #pragma unroll
            for (int j = 0; j < 4; ++j)
                acc[i][j] += xv[i].x*wv4[j].x + xv[i].y*wv4[j].y + xv[i].z*wv4[j].z + xv[i].w*wv4[j].w;
    }
    #pragma unroll
    for (int i = 0; i < 4; ++i)
        #pragma unroll
        for (int j = 0; j < 4; ++j)
            O[(4*ty + i)*64 + tx + 16*j] = f2bf(acc[i][j]);
}

__global__ __launch_bounds__(256) void attn_all_kernel(
    const float* __restrict__ rgb, const float* __restrict__ dep,
    const float* __restrict__ w_exp, const float* __restrict__ b_exp,
    const float* __restrict__ w_rq, const float* __restrict__ w_dq,
    const bf16_t* __restrict__ Kr, const bf16_t* __restrict__ Vr,
    const bf16_t* __restrict__ Kd, const bf16_t* __restrict__ Vd,
    bf16_t* __restrict__ AOr, bf16_t* __restrict__ AOd)
{
    int qt = blockIdx.x;
    int h  = blockIdx.y;
    int z  = blockIdx.z;
    int b = z >> 1, which = z & 1;
    const float* wq = which ? w_dq : w_rq;
    const bf16_t* K = which ? Kr : Kd;
    const bf16_t* V = which ? Vr : Vd;
    bf16_t* AO      = which ? AOd : AOr;

    __shared__ float Xs[64][68];
    __shared__ float Wqs[8][64];
    __shared__ __align__(16) float Ks[4][64][KVSTRIDE];
    __shared__ __align__(16) float Vs[4][64][KVSTRIDE];

    int tid = threadIdx.x;
    int t = tid & 63;
    int w = tid >> 6;
    int n = qt * 64 + t;

    stage_x_row(&Xs[t][0], rgb, dep, w_exp, b_exp, b, n, which == 0 ? 0 : 1, w, 4);
    if (w == 0) {
        #pragma unroll
        for (int d = 0; d < 8; ++d) Wqs[d][t] = wq[(8*h + d)*64 + t];
    }
    __syncthreads();

    const float sc = 0.35355339059327373f * 1.4426950408889634f;
    float q[8];
    #pragma unroll
    for (int d = 0; d < 8; ++d) {
        float s = 0.f;
        #pragma unroll 8
        for (int c = 0; c < 64; ++c) s += Xs[t][c] * Wqs[d][c];
        q[d] = s * sc;
    }

    float mrun = -INFINITY, l = 0.f;
    float acc[8] = {};

    #pragma unroll 1
    for (int st = 0; st < 9; ++st) {
        __syncthreads();
        {
            size_t g = ((size_t)b * NTOK + (w*576 + st*64 + t)) * 64 + 8 * h;
            *(float4*)&Ks[w][t][0] = ld_bf4(&K[g]);
            *(float4*)&Ks[w][t][4] = ld_bf4(&K[g + 4]);
            *(float4*)&Vs[w][t][0] = ld_bf4(&V[g]);
            *(float4*)&Vs[w][t][4] = ld_bf4(&V[g + 4]);
        }
        __syncthreads();

        for (int g8 = 0; g8 < 8; ++g8) {
            float s[8];
            #pragma unroll
            for (int u = 0; u < 8; ++u) {
                const float4 ka = *(const float4*)&Ks[w][g8*8 + u][0];
                const float4 kb = *(const float4*)&Ks[w][g8*8 + u][4];
                s[u] = q[0]*ka.x + q[1]*ka.y + q[2]*ka.z + q[3]*ka.w
                     + q[4]*kb.x + q[5]*kb.y + q[6]*kb.z + q[7]*kb.w;
            }
            float tm = fmaxf(fmaxf(fmaxf(s[0],s[1]), fmaxf(s[2],s[3])),
                             fmaxf(fmaxf(s[4],s[5]), fmaxf(s[6],s[7])));
            float mn = fmaxf(mrun, tm);
            float alpha = __builtin_amdgcn_exp2f(mrun - mn);
            float ps = 0.f;
            #pragma unroll
            for (int u = 0; u < 8; ++u) { s[u] = __builtin_amdgcn_exp2f(s[u] - mn); ps += s[u]; }
            l = l * alpha + ps;
            #pragma unroll
            for (int d = 0; d < 8; ++d) acc[d] *= alpha;
            #pragma unroll
            for (int u = 0; u < 8; ++u) {
                const float4 va = *(const float4*)&Vs[w][g8*8 + u][0];
                const float4 vb = *(const float4*)&Vs[w][g8*8 + u][4];
                acc[0] += s[u]*va.x; acc[1] += s[u]*va.y; acc[2] += s[u]*va.z; acc[3] += s[u]*va.w;
                acc[4] += s[u]*vb.x; acc[5] += s[u]*vb.y; acc[6] += s[u]*vb.z; acc[7] += s[u]*vb.w;
            }
            mrun = mn;
        }
    }

    float* part = &Xs[0][0];
    __syncthreads();
    {
        float* p = &part[(w*64 + t) * 10];
        p[0] = mrun; p[1] = l;
        #pragma unroll
        for (int d = 0; d < 8; ++d) p[2 + d] = acc[d];
    }
    __syncthreads();
    if (tid < 64) {
        float M = -INFINITY;
        #pragma unroll
        for (int v = 0; v < 4; ++v) M = fmaxf(M, part[(v*64 + t)*10]);
        float L = 0.f, o[8] = {};
        #pragma unroll
        for (int v = 0; v < 4; ++v) {
            const float* p = &part[(v*64 + t)*10];
            float al = __builtin_amdgcn_exp2f(p[0] - M);
            L += p[1] * al;
            #pragma unroll
            for (int d = 0; d < 8; ++d) o[d] += p[2 + d] * al;
        }
        float inv = 1.0f / L;
        uint4 ov;
        ov.x = pack2(o[0]*inv, o[1]*inv);
        ov.y = pack2(o[2]*inv, o[3]*inv);
        ov.z = pack2(o[4]*inv, o[5]*inv);
        ov.w = pack2(o[6]*inv, o[7]*inv);
        *(uint4*)&AO[((size_t)b * NTOK + n) * 64 + 8 * h] = ov;
    }
}

__global__ __launch_bounds__(256) void projcomp_all_kernel(
    const bf16_t* __restrict__ AOr, const bf16_t* __restrict__ AOd,
    const float* __restrict__ w_rp, const float* __restrict__ b_rp,
    const float* __restrict__ w_dp, const float* __restrict__ b_dp,
    const float* __restrict__ w_comp, const float* __restrict__ b_comp,
    float* __restrict__ out)
{
    int tile = blockIdx.x;
    int b    = blockIdx.y;
    __shared__ float A[64][68];
    __shared__ float Bf[64][68];
    __shared__ float Pf[64][68];
    int tid = threadIdx.x;
    int sr = tid >> 4, sc = (tid & 15) * 4;
    int ty = tid >> 4, tx = tid & 15;
    float G[4][4] = {};

    #pragma unroll
    for (int half = 0; half < 2; ++half) {
        const bf16_t* AOx = half ? AOd : AOr;
        const float* Wp   = half ? w_dp : w_rp;
        const float* bp   = half ? b_dp : b_rp;
        #pragma unroll
        for (int rr = 0; rr < 4; ++rr) {
            int r = rr*16 + sr;
            *(float4*)&A[r][sc]  = ld_bf4(&AOx[((size_t)b*NTOK + tile*64 + r)*64 + sc]);
            *(float4*)&Bf[r][sc] = *(const float4*)&Wp[r*64 + sc];
        }
        __syncthreads();
        float acc[4][4] = {};
        #pragma unroll
        for (int k = 0; k < 64; k += 4) {
            float4 xv[4], wv[4];
            #pragma unroll
            for (int i = 0; i < 4; ++i) xv[i] = *(const float4*)&A[4*ty + i][k];
            #pragma unroll
            for (int j = 0; j < 4; ++j) wv[j] = *(const float4*)&Bf[tx + 16*j][k];
            #pragma unroll
            for (int i = 0; i < 4; ++i)
                #pragma unroll
                for (int j = 0; j < 4; ++j)
                    acc[i][j] += xv[i].x*wv[j].x + xv[i].y*wv[j].y + xv[i].z*wv[j].z + xv[i].w*wv[j].w;
        }
        __syncthreads();
        #pragma unroll
        for (int j = 0; j < 4; ++j) {
            float bj = bp[tx + 16*j];
            #pragma unroll
            for (int i = 0; i < 4; ++i)
                Pf[4*ty + i][tx + 16*j] = acc[i][j] + bj;
        }
        #pragma unroll
        for (int rr = 0; rr < 4; ++rr) {
            int r = rr*16 + sr;
            *(float4*)&Bf[r][sc] = *(const float4*)&w_comp[r*128 + half*64 + sc];
        }
        __syncthreads();
        #pragma unroll
        for (int k = 0; k < 64; k += 4) {
            float4 xv[4], wv[4];
            #pragma unroll
            for (int i = 0; i < 4; ++i) xv[i] = *(const float4*)&Pf[4*ty + i][k];
            #pragma unroll
            for (int j = 0; j < 4; ++j) wv[j] = *(const float4*)&Bf[tx + 16*j][k];
            #pragma unroll
            for (int i = 0; i < 4; ++i)
                #pragma unroll
                for (int j = 0; j < 4; ++j)
                    G[i][j] += xv[i].x*wv[j].x + xv[i].y*wv[j].y + xv[i].z*wv[j].z + xv[i].w*wv[j].w;
        }
        __syncthreads();
    }

    #pragma unroll
    for (int j = 0; j < 4; ++j) {
        int o = tx + 16*j;
        float bj = b_comp[o];
        #pragma unroll
        for (int i = 0; i < 4; ++i) {
            int n = tile*64 + 4*ty + i;
            int wi = n / HH, hi = n % HH;
            float x = G[i][j] + bj;
            float g = 0.5f * x * (1.0f + erff(x * 0.70710678118654752f));
            out[((b*C + o)*WW + wi)*HH + hi] = g;
        }
    }
}

// ---------------------------------------------------------------------------
extern "C" void kernel_launch(void* const* d_in, const int* in_sizes, int n_in,
                              void* d_out, int out_size, void* d_ws, size_t ws_size,
                              hipStream_t stream) {
    const float* rgb_fea = (const float*)d_in[0];
    const float* depth   = (const float*)d_in[1];
    const float* w_exp   = (const float*)d_in[2];
    const float* b_exp   = (const float*)d_in[3];
    const float* w_rq    = (const float*)d_in[4];
    const float* w_rk    = (const float*)d_in[5];
    const float* w_rv    = (const float*)d_in[6];
    const float* w_dq    = (const float*)d_in[7];
    const float* w_dk    = (const float*)d_in[8];
    const float* w_dv    = (const float*)d_in[9];
    const float* w_rp    = (const float*)d_in[10];
    const float* b_rp    = (const float*)d_in[11];
    const float* w_dp    = (const float*)d_in[12];
    const float* b_dp    = (const float*)d_in[13];
    const float* w_comp  = (const float*)d_in[14];
    const float* b_comp  = (const float*)d_in[15];
    float* out = (float*)d_out;

    if (ws_size >= 5931264) {
        // Layout (same as R16 T1):
        //   0        Qb [4][8][2304][8] bf16   (1,179,648)
        //   1179648  Kb                        (1,179,648)
        //   2359296  VT [4][8][8][2304] bf16   (1,179,648)
        //   3538944  XtAO: Xt [4][2304][64] f32 == AOr+AOd (2,359,296)
        //   5898240  W1 / 5914624 W2 / 5931008 beff
        char* Wb = (char*)d_ws;
        bf16_t* Qb   = (bf16_t*)Wb;
        bf16_t* Kb   = (bf16_t*)(Wb + 1179648);
        bf16_t* VT   = (bf16_t*)(Wb + 2359296);
        float*  XtAO = (float*)(Wb + 3538944);
        float*  AOr  = XtAO;
        float*  AOd  = XtAO + 294912;
        float*  W1   = (float*)(Wb + 5898240);
        float*  W2   = (float*)(Wb + 5914624);
        float*  beff = (float*)(Wb + 5931008);
        float*  Xt   = XtAO;   // dead after qkv; attn overwrites as AO

        prep_kernel<<<dim3(152), dim3(256), 0, stream>>>(
            rgb_fea, depth, w_exp, b_exp, w_rp, w_dp, w_comp,
            b_rp, b_dp, b_comp, Xt, W1, W2, beff);
        qkv_kernel<<<dim3(144, 4), dim3(256), 0, stream>>>(
            Xt, w_rq, w_rk, w_rv, w_dq, w_dk, w_dv, Qb, Kb, VT);
        attn_kernel<<<dim3(36, 8, 4), dim3(256), 0, stream>>>(
            Qb, Kb, VT, AOr, AOd);
        outcomp_kernel<<<dim3(144, 2), dim3(256), 0, stream>>>(
            AOr, AOd, W1, W2, beff, out);
    } else {
        // R9 big path (proven)
        const size_t BUF = (size_t)BATCH * NTOK * 64;
        bf16_t* Kr  = (bf16_t*)d_ws;
        bf16_t* Vr  = Kr + BUF;
        bf16_t* Kd  = Vr + BUF;
        bf16_t* Vd  = Kd + BUF;
        bf16_t* AOr = Vd + BUF;
        bf16_t* AOd = AOr + BUF;
        kv_all_kernel<<<dim3(36, 2, 4), dim3(256), 0, stream>>>(
            rgb_fea, depth, w_exp, b_exp, w_rk, w_rv, w_dk, w_dv, Kr, Vr, Kd, Vd);
        attn_all_kernel<<<dim3(36, 8, 4), dim3(256), 0, stream>>>(
            rgb_fea, depth, w_exp, b_exp, w_rq, w_dq, Kr, Vr, Kd, Vd, AOr, AOd);
        projcomp_all_kernel<<<dim3(36, 2), dim3(256), 0, stream>>>(
            AOr, AOd, w_rp, b_rp, w_dp, b_dp, w_comp, b_comp, out);
    }
}

// Round 8
// 161.484 us; speedup vs baseline: 1.6674x; 1.0304x over previous
//
#include <hip/hip_runtime.h>
#include <math.h>

// R23: R22=166.4us. attn is INVARIANT at ~52.8us across: occupancy 2x (R17,
// slower), load prefetch (R21, slower), DS ops 3x fewer (R22, same). No pipe
// >41% busy. All in-kernel hypotheses falsified -> consistent explanation:
// short dispatches run at un-ramped clock (~1GHz from VALU-cycle math), so
// each dispatch carries a large quasi-fixed cost (all kernels always land
// 25-65us regardless of content). Lever: FEWER dispatches without
// serializing (R20's mistake). Delete prep: qkv gathers X directly via
// proven stage_x_row (4 scalar loads/thread, hidden under weight prefetch);
// wprep folds in as 8 blocks (grid(146,4)). Xt gone; bit-identical math.
// 4 dispatches -> 3. attn/outcomp/fallback untouched (R22 proven).
#define BATCH 2
#define C 64
#define HH 48
#define WW 48
#define NTOK 2304
#define HEADS 8
#define KVSTRIDE 12

typedef unsigned short bf16_t;
typedef __attribute__((ext_vector_type(8))) short bf16x8;
typedef __attribute__((ext_vector_type(4))) short bf16x4;
typedef __attribute__((ext_vector_type(4))) float f32x4;

__device__ __forceinline__ bf16_t f2bf(float f) {
    unsigned int u = __float_as_uint(f);
    u = (u + 0x7fffu + ((u >> 16) & 1u)) >> 16;   // RNE
    return (bf16_t)u;
}
__device__ __forceinline__ unsigned pack2(float a, float b) {
    return (unsigned)f2bf(a) | ((unsigned)f2bf(b) << 16);
}
__device__ __forceinline__ float4 ld_bf4(const bf16_t* p) {
    uint2 v = *(const uint2*)p;
    float4 r;
    r.x = __uint_as_float(v.x << 16); r.y = __uint_as_float(v.x & 0xffff0000u);
    r.z = __uint_as_float(v.y << 16); r.w = __uint_as_float(v.y & 0xffff0000u);
    return r;
}

// Stage one token-row of X. strm 0: rgb transpose gather. strm 1: conv1x1+
// ReLU+bilinear x2 (half-pixel; clamp == jax edge renorm for 24->48).
__device__ __forceinline__ void stage_x_row(
    float* xrow, const float* rgb, const float* dep,
    const float* w_exp, const float* b_exp,
    int b, int n, int strm, int c0, int cstep)
{
    int wi = n / HH, hi = n % HH;
    if (strm == 0) {
        const float* base = rgb + (size_t)b * C * NTOK + (size_t)hi * WW + wi;
        for (int c = c0; c < 64; c += cstep)
            xrow[c] = base[(size_t)c * NTOK];
    } else {
        float cy = 0.5f * hi - 0.25f, cx = 0.5f * wi - 0.25f;
        float fy0 = floorf(cy), fx0 = floorf(cx);
        float fy = cy - fy0, fx = cx - fx0;
        int y0 = max((int)fy0, 0), x0 = max((int)fx0, 0);
        int y1 = min((int)fy0 + 1, 23), x1 = min((int)fx0 + 1, 23);
        const float* dp = dep + b * 576;
        float d00 = dp[y0*24 + x0], d01 = dp[y0*24 + x1];
        float d10 = dp[y1*24 + x0], d11 = dp[y1*24 + x1];
        for (int c = c0; c < 64; c += cstep) {
            float w = w_exp[c], bb = b_exp[c];
            float r00 = fmaxf(w*d00 + bb, 0.f), r01 = fmaxf(w*d01 + bb, 0.f);
            float r10 = fmaxf(w*d10 + bb, 0.f), r11 = fmaxf(w*d11 + bb, 0.f);
            xrow[c] = (1.f-fy)*((1.f-fx)*r00 + fx*r01) + fy*((1.f-fx)*r10 + fx*r11);
        }
    }
}

// ===========================================================================
// MAIN PATH: 3 dispatches (qkvprep, attn, outcomp).
// ===========================================================================

// qkvprep: grid(146, 4). Blocks x<144: 16-token tile x (b*2+strm); X
// gathered in-block via stage_x_row (proven), weights register-prefetched
// upfront (proven R21/R22), 3 GEMM phases. Blocks x in {144,145}: wprep
// task m = x-144, bx = blockIdx.y (proven R20 body).
// Q,K -> [sb][h][n][8] bf16 (Q pre-scaled); V -> [sb][h][d][n].
__global__ __launch_bounds__(256) void qkvprep_kernel(
    const float* __restrict__ rgb, const float* __restrict__ dep,
    const float* __restrict__ w_exp, const float* __restrict__ b_exp,
    const float* __restrict__ w_rq, const float* __restrict__ w_rk,
    const float* __restrict__ w_rv,
    const float* __restrict__ w_dq, const float* __restrict__ w_dk,
    const float* __restrict__ w_dv,
    const float* __restrict__ w_rp, const float* __restrict__ w_dp,
    const float* __restrict__ w_comp,
    const float* __restrict__ b_rp, const float* __restrict__ b_dp,
    const float* __restrict__ b_comp,
    bf16_t* __restrict__ Qb, bf16_t* __restrict__ Kb, bf16_t* __restrict__ VT,
    float* __restrict__ W1, float* __restrict__ W2, float* __restrict__ beff)
{
    __shared__ float Xs[16][68];
    __shared__ float Ws[64][68];
    int bxid = blockIdx.x;
    int tid = threadIdx.x;
    int sr = tid >> 4, sc = (tid & 15) * 4;

    if (bxid < 144) {
        int tile = bxid;
        int z = blockIdx.y;              // b*2 + strm
        int b = z >> 1, strm = z & 1;
        int sb = strm*2 + b;

        // Issue ALL weight loads first (independent of the X gather).
        float4 wreg[3][4];
        #pragma unroll
        for (int m = 0; m < 3; ++m) {
            const float* W = strm ? (m == 0 ? w_dq : m == 1 ? w_dk : w_dv)
                                  : (m == 0 ? w_rq : m == 1 ? w_rk : w_rv);
            #pragma unroll
            for (int rr = 0; rr < 4; ++rr)
                wreg[m][rr] = *(const float4*)&W[(rr*16 + sr)*64 + sc];
        }
        {
            int r = tid & 15, c0 = tid >> 4;   // 16 threads per token row
            stage_x_row(&Xs[r][0], rgb, dep, w_exp, b_exp,
                        b, tile*16 + r, strm, c0, 16);
        }

        int ty = tid >> 4, tx = tid & 15;
        #pragma unroll
        for (int m = 0; m < 3; ++m) {
            __syncthreads();   // Xs ready (m=0) / prior GEMM done reading Ws
            #pragma unroll
            for (int rr = 0; rr < 4; ++rr)
                *(float4*)&Ws[rr*16 + sr][sc] = wreg[m][rr];
            __syncthreads();

            float acc[4] = {};
            #pragma unroll
            for (int k = 0; k < 64; k += 4) {
                float4 xv = *(const float4*)&Xs[ty][k];
                #pragma unroll
                for (int j = 0; j < 4; ++j) {
                    float4 wv = *(const float4*)&Ws[tx + 16*j][k];
                    acc[j] += xv.x*wv.x + xv.y*wv.y + xv.z*wv.z + xv.w*wv.w;
                }
            }
            float scale = (m == 0) ? (0.35355339059327373f * 1.4426950408889634f) : 1.0f;
            int n = tile*16 + ty;
            #pragma unroll
            for (int j = 0; j < 4; ++j) {
                int o = tx + 16*j;
                int h = o >> 3, d = o & 7;
                bf16_t v = f2bf(acc[j] * scale);
                if (m == 0)      Qb[(((size_t)sb*8 + h)*NTOK + n)*8 + d] = v;
                else if (m == 1) Kb[(((size_t)sb*8 + h)*NTOK + n)*8 + d] = v;
                else             VT[(((size_t)sb*8 + h)*8 + d)*NTOK + n] = v;
            }
        }
    } else {
        // wprep: m = bxid-144 (0: W1=Wc[:,:64]@Wrp, 1: W2=Wc[:,64:]@Wdp),
        // bx = blockIdx.y selects the 16-row output strip.
        int m = bxid - 144;
        int bx = blockIdx.y;
        const float* Wp = m ? w_dp : w_rp;
        float* Wo = m ? W2 : W1;
        #pragma unroll
        for (int rr = 0; rr < 4; ++rr) {
            int r = rr*16 + sr;
            *(float4*)&Ws[r][sc] = *(const float4*)&Wp[r*64 + sc];
        }
        __syncthreads();
        int r = tid >> 4;
        int o = bx*16 + r;
        int c4 = (tid & 15) * 4;
        float a0 = 0, a1 = 0, a2 = 0, a3 = 0;
        for (int j = 0; j < 64; ++j) {
            float wc = w_comp[o*128 + m*64 + j];
            float4 wp = *(const float4*)&Ws[j][c4];
            a0 += wc*wp.x; a1 += wc*wp.y; a2 += wc*wp.z; a3 += wc*wp.w;
        }
        Wo[o*64 + c4]     = a0;
        Wo[o*64 + c4 + 1] = a1;
        Wo[o*64 + c4 + 2] = a2;
        Wo[o*64 + c4 + 3] = a3;
        if (m == 0 && bx == 0 && tid < 64) {
            float s = b_comp[tid];
            for (int j = 0; j < 64; ++j)
                s += w_comp[tid*128 + j] * b_rp[j] + w_comp[tid*128 + 64 + j] * b_dp[j];
            beff[tid] = s;
        }
    }
}

// MFMA flash attention, swapped-operand S^T + packed b64 P stores (R22,
// proven). grid(36, 8, 4); 4 independent waves; wave w = qtile bx*4+w.
__global__ __launch_bounds__(256) void attn_kernel(
    const bf16_t* __restrict__ Qb, const bf16_t* __restrict__ Kb,
    const bf16_t* __restrict__ VT,
    float* __restrict__ AOr, float* __restrict__ AOd)
{
    int h = blockIdx.y;
    int z = blockIdx.z;
    int b = z >> 1, which = z & 1;
    int qsb = which * 2 + b;
    int ksb = (1 - which) * 2 + b;
    const bf16_t* Q  = Qb + ((size_t)qsb * 8 + h) * NTOK * 8;
    const bf16_t* K  = Kb + ((size_t)ksb * 8 + h) * NTOK * 8;
    const bf16_t* Vt = VT + ((size_t)ksb * 8 + h) * 8 * NTOK;  // [d][key]
    float* AO = which ? AOd : AOr;

    __shared__ __align__(16) bf16_t Pls[4][16][40];  // 5 KB, rows 80 B
    __shared__ __align__(16) float  Ols[4][16][16];  // 4 KB

    int tid = threadIdx.x;
    int t = tid & 63, w = tid >> 6;
    int m16 = t & 15, quad = t >> 4;
    int qt = blockIdx.x * 4 + w;       // 0..143
    int n0 = qt * 16;

    const bf16x8 zf = {0,0,0,0,0,0,0,0};
    const bf16x8 onesf = {0x3F80,0x3F80,0x3F80,0x3F80,
                          0x3F80,0x3F80,0x3F80,0x3F80};
    const f32x4 cz = {0.f, 0.f, 0.f, 0.f};

    bf16x8 qf = (quad == 0) ? *(const bf16x8*)&Q[(size_t)(n0 + m16) * 8] : zf;

    f32x4 oacc = cz;

    #pragma unroll 1
    for (int ck = 0; ck < 72; ++ck) {
        int k0 = ck * 32;
        bf16x8 kf0 = (quad == 0) ? *(const bf16x8*)&K[(size_t)(k0 + m16) * 8]      : zf;
        bf16x8 kf1 = (quad == 0) ? *(const bf16x8*)&K[(size_t)(k0 + 16 + m16) * 8] : zf;
        bf16x8 vf = (m16 < 8) ? *(const bf16x8*)&Vt[(size_t)m16 * NTOK + k0 + quad * 8]
                  : (m16 == 8 ? onesf : zf);

        f32x4 s0 = __builtin_amdgcn_mfma_f32_16x16x32_bf16(kf0, qf, cz, 0, 0, 0);
        f32x4 s1 = __builtin_amdgcn_mfma_f32_16x16x32_bf16(kf1, qf, cz, 0, 0, 0);

        bf16x4 pA, pB;
        #pragma unroll
        for (int r = 0; r < 4; ++r) {
            float p0 = __builtin_amdgcn_exp2f(s0[r]);
            float p1 = __builtin_amdgcn_exp2f(s1[r]);
            pA[r] = (short)(__float_as_uint(p0) >> 16);
            pB[r] = (short)(__float_as_uint(p1) >> 16);
        }
        *(bf16x4*)&Pls[w][m16][quad * 4]      = pA;
        *(bf16x4*)&Pls[w][m16][16 + quad * 4] = pB;

        bf16x8 pf = *(const bf16x8*)&Pls[w][m16][quad * 8];
        oacc = __builtin_amdgcn_mfma_f32_16x16x32_bf16(pf, vf, oacc, 0, 0, 0);
    }

    #pragma unroll
    for (int r = 0; r < 4; ++r)
        Ols[w][quad*4 + r][m16] = oacc[r];
    #pragma unroll
    for (int e = 0; e < 2; ++e) {
        int idx = t * 2 + e;           // 0..127 = 16 q x 8 d
        int qq = idx >> 3, d = idx & 7;
        float val = Ols[w][qq][d] / Ols[w][qq][8];
        AO[((size_t)b * NTOK + n0 + qq) * 64 + 8 * h + d] = val;
    }
}

// Fused 2x K=64 GEMM + beff + GELU + LDS-restage + coalesced store.
// grid(144, 2): 16-token tiles (288 blocks). Proven R21/R22.
__global__ __launch_bounds__(256) void outcomp_kernel(
    const float* __restrict__ AOr, const float* __restrict__ AOd,
    const float* __restrict__ W1, const float* __restrict__ W2,
    const float* __restrict__ beff, float* __restrict__ out)
{
    int tile = blockIdx.x;       // 0..143
    int b    = blockIdx.y;
    int n0 = tile * 16;
    __shared__ float Ar[16][68];
    __shared__ float Ad[16][68];
    __shared__ float W1s[64][68];
    __shared__ float W2s[64][68];
    int tid = threadIdx.x;
    {
        int row = tid >> 4, c4 = (tid & 15) * 4;
        size_t base = (size_t)b*NTOK + n0 + row;
        *(float4*)&Ar[row][c4] = *(const float4*)&AOr[base*64 + c4];
        *(float4*)&Ad[row][c4] = *(const float4*)&AOd[base*64 + c4];
    }
    {
        int sr = tid >> 4, sc4 = (tid & 15) * 4;
        #pragma unroll
        for (int rr = 0; rr < 4; ++rr) {
            int r = rr*16 + sr;
            *(float4*)&W1s[r][sc4] = *(const float4*)&W1[r*64 + sc4];
            *(float4*)&W2s[r][sc4] = *(const float4*)&W2[r*64 + sc4];
        }
    }
    __syncthreads();

    int tx = tid & 15, ty = tid >> 4;
    float g[4] = {};
    #pragma unroll
    for (int k = 0; k < 64; k += 4) {
        float4 xr = *(const float4*)&Ar[ty][k];
        float4 xd = *(const float4*)&Ad[ty][k];
        #pragma unroll
        for (int jj = 0; jj < 4; ++jj) {
            float4 w1 = *(const float4*)&W1s[tx + 16*jj][k];
            float4 w2 = *(const float4*)&W2s[tx + 16*jj][k];
            g[jj] += xr.x*w1.x + xr.y*w1.y + xr.z*w1.z + xr.w*w1.w
                   + xd.x*w2.x + xd.y*w2.y + xd.z*w2.z + xd.w*w2.w;
        }
    }

    __syncthreads();                   // done reading W1s/W2s
    float* Gs = &W1s[0][0];            // viewed as [64 o][stride 20]
    #pragma unroll
    for (int jj = 0; jj < 4; ++jj) {
        int o = tx + 16*jj;
        float x = g[jj] + beff[o];
        float gl = 0.5f * x * (1.0f + erff(x * 0.70710678118654752f));
        Gs[o*20 + ty] = gl;
    }
    __syncthreads();
    {
        int o = tid >> 2, s = tid & 3;  // 64 o x 4 float4-segments
        float4 v = *(const float4*)&Gs[o*20 + 4*s];
        *(float4*)&out[((size_t)(b*C + o))*NTOK + n0 + 4*s] = v;
    }
}

// ===========================================================================
// FALLBACK (R9 big path, proven): ws >= 3,538,944 B.
// ===========================================================================
__global__ __launch_bounds__(256) void kv_all_kernel(
    const float* __restrict__ rgb, const float* __restrict__ dep,
    const float* __restrict__ w_exp, const float* __restrict__ b_exp,
    const float* __restrict__ w_rk, const float* __restrict__ w_rv,
    const float* __restrict__ w_dk, const float* __restrict__ w_dv,
    bf16_t* __restrict__ Kr, bf16_t* __restrict__ Vr,
    bf16_t* __restrict__ Kd, bf16_t* __restrict__ Vd)
{
    int tile = blockIdx.x;
    int m    = blockIdx.y;
    int z    = blockIdx.z;
    int b = z >> 1, strm = z & 1;
    const float* W = strm ? (m ? w_dv : w_dk) : (m ? w_rv : w_rk);
    bf16_t* O = (strm ? (m ? Vd : Kd) : (m ? Vr : Kr))
              + ((size_t)b * NTOK + tile * 64) * 64;

    __shared__ float Xs[64][68];
    __shared__ float Ws[64][68];
    int tid = threadIdx.x;
    {
        int r = tid & 63, c0 = tid >> 6;
        stage_x_row(&Xs[r][0], rgb, dep, w_exp, b_exp, b, tile*64 + r, strm, c0, 4);
    }
    int sr = tid >> 4, sc = (tid & 15) * 4;
    #pragma unroll
    for (int rr = 0; rr < 4; ++rr) {
        int r = rr*16 + sr;
        *(float4*)&Ws[r][sc] = *(const float4*)&W[r*64 + sc];
    }
    __syncthreads();

    int ty = tid >> 4, tx = tid & 15;
    float acc[4][4] = {};
    #pragma unroll
    for (int k = 0; k < 64; k += 4) {
        float4 xv[4], wv4[4];
        #pragma unroll
        for (int i = 0; i < 4; ++i) xv[i] = *(const float4*)&Xs[4*ty + i][k];
        #pragma unroll
        for (int j = 0; j < 4; ++j) wv4[j] = *(const float4*)&Ws[tx + 16*j][k];
        #pragma unroll
        for (int i = 0; i < 4; ++i)
            #pragma unroll
            for (int j = 0; j < 4; ++j)
                acc[i][j] += xv[i].x*wv4[j].x + xv[i].y*wv4[j].y + xv[i].z*wv4[j].z + xv[i].w*wv4[j].w;
    }
    #pragma unroll
    for (int i = 0; i < 4; ++i)
        #pragma unroll
        for (int j = 0; j < 4; ++j)
            O[(4*ty + i)*64 + tx + 16*j] = f2bf(acc[i][j]);
}

__global__ __launch_bounds__(256) void attn_all_kernel(
    const float* __restrict__ rgb, const float* __restrict__ dep,
    const float* __restrict__ w_exp, const float* __restrict__ b_exp,
    const float* __restrict__ w_rq, const float* __restrict__ w_dq,
    const bf16_t* __restrict__ Kr, const bf16_t* __restrict__ Vr,
    const bf16_t* __restrict__ Kd, const bf16_t* __restrict__ Vd,
    bf16_t* __restrict__ AOr, bf16_t* __restrict__ AOd)
{
    int qt = blockIdx.x;
    int h  = blockIdx.y;
    int z  = blockIdx.z;
    int b = z >> 1, which = z & 1;
    const float* wq = which ? w_dq : w_rq;
    const bf16_t* K = which ? Kr : Kd;
    const bf16_t* V = which ? Vr : Vd;
    bf16_t* AO      = which ? AOd : AOr;

    __shared__ float Xs[64][68];
    __shared__ float Wqs[8][64];
    __shared__ __align__(16) float Ks[4][64][KVSTRIDE];
    __shared__ __align__(16) float Vs[4][64][KVSTRIDE];

    int tid = threadIdx.x;
    int t = tid & 63;
    int w = tid >> 6;
    int n = qt * 64 + t;

    stage_x_row(&Xs[t][0], rgb, dep, w_exp, b_exp, b, n, which == 0 ? 0 : 1, w, 4);
    if (w == 0) {
        #pragma unroll
        for (int d = 0; d < 8; ++d) Wqs[d][t] = wq[(8*h + d)*64 + t];
    }
    __syncthreads();

    const float sc = 0.35355339059327373f * 1.4426950408889634f;
    float q[8];
    #pragma unroll
    for (int d = 0; d < 8; ++d) {
        float s = 0.f;
        #pragma unroll 8
        for (int c = 0; c < 64; ++c) s += Xs[t][c] * Wqs[d][c];
        q[d] = s * sc;
    }

    float mrun = -INFINITY, l = 0.f;
    float acc[8] = {};

    #pragma unroll 1
    for (int st = 0; st < 9; ++st) {
        __syncthreads();
        {
            size_t g = ((size_t)b * NTOK + (w*576 + st*64 + t)) * 64 + 8 * h;
            *(float4*)&Ks[w][t][0] = ld_bf4(&K[g]);
            *(float4*)&Ks[w][t][4] = ld_bf4(&K[g + 4]);
            *(float4*)&Vs[w][t][0] = ld_bf4(&V[g]);
            *(float4*)&Vs[w][t][4] = ld_bf4(&V[g + 4]);
        }
        __syncthreads();

        for (int g8 = 0; g8 < 8; ++g8) {
            float s[8];
            #pragma unroll
            for (int u = 0; u < 8; ++u) {
                const float4 ka = *(const float4*)&Ks[w][g8*8 + u][0];
                const float4 kb = *(const float4*)&Ks[w][g8*8 + u][4];
                s[u] = q[0]*ka.x + q[1]*ka.y + q[2]*ka.z + q[3]*ka.w
                     + q[4]*kb.x + q[5]*kb.y + q[6]*kb.z + q[7]*kb.w;
            }
            float tm = fmaxf(fmaxf(fmaxf(s[0],s[1]), fmaxf(s[2],s[3])),
                             fmaxf(fmaxf(s[4],s[5]), fmaxf(s[6],s[7])));
            float mn = fmaxf(mrun, tm);
            float alpha = __builtin_amdgcn_exp2f(mrun - mn);
            float ps = 0.f;
            #pragma unroll
            for (int u = 0; u < 8; ++u) { s[u] = __builtin_amdgcn_exp2f(s[u] - mn); ps += s[u]; }
            l = l * alpha + ps;
            #pragma unroll
            for (int d = 0; d < 8; ++d) acc[d] *= alpha;
            #pragma unroll
            for (int u = 0; u < 8; ++u) {
                const float4 va = *(const float4*)&Vs[w][g8*8 + u][0];
                const float4 vb = *(const float4*)&Vs[w][g8*8 + u][4];
                acc[0] += s[u]*va.x; acc[1] += s[u]*va.y; acc[2] += s[u]*va.z; acc[3] += s[u]*va.w;
                acc[4] += s[u]*vb.x; acc[5] += s[u]*vb.y; acc[6] += s[u]*vb.z; acc[7] += s[u]*vb.w;
            }
            mrun = mn;
        }
    }

    float* part = &Xs[0][0];
    __syncthreads();
    {
        float* p = &part[(w*64 + t) * 10];
        p[0] = mrun; p[1] = l;
        #pragma unroll
        for (int d = 0; d < 8; ++d) p[2 + d] = acc[d];
    }
    __syncthreads();
    if (tid < 64) {
        float M = -INFINITY;
        #pragma unroll
        for (int v = 0; v < 4; ++v) M = fmaxf(M, part[(v*64 + t)*10]);
        float L = 0.f, o[8] = {};
        #pragma unroll
        for (int v = 0; v < 4; ++v) {
            const float* p = &part[(v*64 + t)*10];
            float al = __builtin_amdgcn_exp2f(p[0] - M);
            L += p[1] * al;
            #pragma unroll
            for (int d = 0; d < 8; ++d) o[d] += p[2 + d] * al;
        }
        float inv = 1.0f / L;
        uint4 ov;
        ov.x = pack2(o[0]*inv, o[1]*inv);
        ov.y = pack2(o[2]*inv, o[3]*inv);
        ov.z = pack2(o[4]*inv, o[5]*inv);
        ov.w = pack2(o[6]*inv, o[7]*inv);
        *(uint4*)&AO[((size_t)b * NTOK + n) * 64 + 8 * h] = ov;
    }
}

__global__ __launch_bounds__(256) void projcomp_all_kernel(
    const bf16_t* __restrict__ AOr, const bf16_t* __restrict__ AOd,
    const float* __restrict__ w_rp, const float* __restrict__ b_rp,
    const float* __restrict__ w_dp, const float* __restrict__ b_dp,
    const float* __restrict__ w_comp, const float* __restrict__ b_comp,
    float* __restrict__ out)
{
    int tile = blockIdx.x;
    int b    = blockIdx.y;
    __shared__ float A[64][68];
    __shared__ float Bf[64][68];
    __shared__ float Pf[64][68];
    int tid = threadIdx.x;
    int sr = tid >> 4, sc = (tid & 15) * 4;
    int ty = tid >> 4, tx = tid & 15;
    float G[4][4] = {};

    #pragma unroll
    for (int half = 0; half < 2; ++half) {
        const bf16_t* AOx = half ? AOd : AOr;
        const float* Wp   = half ? w_dp : w_rp;
        const float* bp   = half ? b_dp : b_rp;
        #pragma unroll
        for (int rr = 0; rr < 4; ++rr) {
            int r = rr*16 + sr;
            *(float4*)&A[r][sc]  = ld_bf4(&AOx[((size_t)b*NTOK + tile*64 + r)*64 + sc]);
            *(float4*)&Bf[r][sc] = *(const float4*)&Wp[r*64 + sc];
        }
        __syncthreads();
        float acc[4][4] = {};
        #pragma unroll
        for (int k = 0; k < 64; k += 4) {
            float4 xv[4], wv[4];
            #pragma unroll
            for (int i = 0; i < 4; ++i) xv[i] = *(const float4*)&A[4*ty + i][k];
            #pragma unroll
            for (int j = 0; j < 4; ++j) wv[j] = *(const float4*)&Bf[tx + 16*j][k];
            #pragma unroll
            for (int i = 0; i < 4; ++i)
                #pragma unroll
                for (int j = 0; j < 4; ++j)
                    acc[i][j] += xv[i].x*wv[j].x + xv[i].y*wv[j].y + xv[i].z*wv[j].z + xv[i].w*wv[j].w;
        }
        __syncthreads();
        #pragma unroll
        for (int j = 0; j < 4; ++j) {
            float bj = bp[tx + 16*j];
            #pragma unroll
            for (int i = 0; i < 4; ++i)
                Pf[4*ty + i][tx + 16*j] = acc[i][j] + bj;
        }
        #pragma unroll
        for (int rr = 0; rr < 4; ++rr) {
            int r = rr*16 + sr;
            *(float4*)&Bf[r][sc] = *(const float4*)&w_comp[r*128 + half*64 + sc];
        }
        __syncthreads();
        #pragma unroll
        for (int k = 0; k < 64; k += 4) {
            float4 xv[4], wv[4];
            #pragma unroll
            for (int i = 0; i < 4; ++i) xv[i] = *(const float4*)&Pf[4*ty + i][k];
            #pragma unroll
            for (int j = 0; j < 4; ++j) wv[j] = *(const float4*)&Bf[tx + 16*j][k];
            #pragma unroll
            for (int i = 0; i < 4; ++i)
                #pragma unroll
                for (int j = 0; j < 4; ++j)
                    G[i][j] += xv[i].x*wv[j].x + xv[i].y*wv[j].y + xv[i].z*wv[j].z + xv[i].w*wv[j].w;
        }
        __syncthreads();
    }

    #pragma unroll
    for (int j = 0; j < 4; ++j) {
        int o = tx + 16*j;
        float bj = b_comp[o];
        #pragma unroll
        for (int i = 0; i < 4; ++i) {
            int n = tile*64 + 4*ty + i;
            int wi = n / HH, hi = n % HH;
            float x = G[i][j] + bj;
            float g = 0.5f * x * (1.0f + erff(x * 0.70710678118654752f));
            out[((b*C + o)*WW + wi)*HH + hi] = g;
        }
    }
}

// ---------------------------------------------------------------------------
extern "C" void kernel_launch(void* const* d_in, const int* in_sizes, int n_in,
                              void* d_out, int out_size, void* d_ws, size_t ws_size,
                              hipStream_t stream) {
    const float* rgb_fea = (const float*)d_in[0];
    const float* depth   = (const float*)d_in[1];
    const float* w_exp   = (const float*)d_in[2];
    const float* b_exp   = (const float*)d_in[3];
    const float* w_rq    = (const float*)d_in[4];
    const float* w_rk    = (const float*)d_in[5];
    const float* w_rv    = (const float*)d_in[6];
    const float* w_dq    = (const float*)d_in[7];
    const float* w_dk    = (const float*)d_in[8];
    const float* w_dv    = (const float*)d_in[9];
    const float* w_rp    = (const float*)d_in[10];
    const float* b_rp    = (const float*)d_in[11];
    const float* w_dp    = (const float*)d_in[12];
    const float* b_dp    = (const float*)d_in[13];
    const float* w_comp  = (const float*)d_in[14];
    const float* b_comp  = (const float*)d_in[15];
    float* out = (float*)d_out;

    if (ws_size >= 5931264) {
        // Layout (unchanged; Xt slot now unused):
        //   0        Qb [4][8][2304][8] bf16   (1,179,648)
        //   1179648  Kb                        (1,179,648)
        //   2359296  VT [4][8][8][2304] bf16   (1,179,648)
        //   3538944  AOr+AOd [2x 2304*64*2] f32 (2,359,296)
        //   5898240  W1 / 5914624 W2 / 5931008 beff
        char* Wb = (char*)d_ws;
        bf16_t* Qb   = (bf16_t*)Wb;
        bf16_t* Kb   = (bf16_t*)(Wb + 1179648);
        bf16_t* VT   = (bf16_t*)(Wb + 2359296);
        float*  AOr  = (float*)(Wb + 3538944);
        float*  AOd  = AOr + 294912;
        float*  W1   = (float*)(Wb + 5898240);
        float*  W2   = (float*)(Wb + 5914624);
        float*  beff = (float*)(Wb + 5931008);

        qkvprep_kernel<<<dim3(146, 4), dim3(256), 0, stream>>>(
            rgb_fea, depth, w_exp, b_exp,
            w_rq, w_rk, w_rv, w_dq, w_dk, w_dv,
            w_rp, w_dp, w_comp, b_rp, b_dp, b_comp,
            Qb, Kb, VT, W1, W2, beff);
        attn_kernel<<<dim3(36, 8, 4), dim3(256), 0, stream>>>(
            Qb, Kb, VT, AOr, AOd);
        outcomp_kernel<<<dim3(144, 2), dim3(256), 0, stream>>>(
            AOr, AOd, W1, W2, beff, out);
    } else {
        // R9 big path (proven)
        const size_t BUF = (size_t)BATCH * NTOK * 64;
        bf16_t* Kr  = (bf16_t*)d_ws;
        bf16_t* Vr  = Kr + BUF;
        bf16_t* Kd  = Vr + BUF;
        bf16_t* Vd  = Kd + BUF;
        bf16_t* AOr = Vd + BUF;
        bf16_t* AOd = AOr + BUF;
        kv_all_kernel<<<dim3(36, 2, 4), dim3(256), 0, stream>>>(
            rgb_fea, depth, w_exp, b_exp, w_rk, w_rv, w_dk, w_dv, Kr, Vr, Kd, Vd);
        attn_all_kernel<<<dim3(36, 8, 4), dim3(256), 0, stream>>>(
            rgb_fea, depth, w_exp, b_exp, w_rq, w_dq, Kr, Vr, Kd, Vd, AOr, AOd);
        projcomp_all_kernel<<<dim3(36, 2), dim3(256), 0, stream>>>(
            AOr, AOd, w_rp, b_rp, w_dp, b_dp, w_comp, b_comp, out);
    }
}